// Round 6
// baseline (1878.115 us; speedup 1.0000x reference)
//
#include <hip/hip_runtime.h>
#include <cstdint>
#include <cstddef>

// LSTMClassifier R12: shrink the L2 serial region around the h2 detect.
// Postmortems R7-R11: traffic, RTT-count, VALU, issue-timing all null; cycle budget
// invariant ~5000cy/step @ ~740MHz effective. Step = ~2 loaded LLC RTTs + ~2.8us of
// SERIAL compute/staging. R12 restructures L2:
//  - h1 staging hoisted to previous step's tail (always prefetch-hit; off fresh path).
//  - own-K-first Whh2: own 64 h2 cols written to LDS at publish; step runs Wih2(8ks)
//    + own-K Whh2(2ks) BEFORE the foreign wait -> ~480cy arrival headroom; only 6ks
//    MFMA + cell remain after detect.
//  - Wh registers loaded ROTATED by 2q so own K-slots are compile-time i=0,1 (no
//    runtime-indexed reg arrays); LDS col base cb[i] is runtime (cheap).
//  - foreign poll = 12 packets/thread (192 cols); barriers 3 -> 2 per step.
// L1 kept identical to R11 (proven). Tagged packets + hot spins retained.

constexpr int kN = 36, kH = 256, kG = 1024, kB = 32, kT = 128, kSpec = 6, kOut = 30;
constexpr int kHP = 264;   // LDS h stride (ushort)
constexpr int kD1 = 16;    // h1 ring depth (steps)

typedef __bf16 bf16;
typedef __bf16 bf16x8 __attribute__((ext_vector_type(8)));
typedef float f32x4 __attribute__((ext_vector_type(4)));
typedef unsigned long long u64;
typedef unsigned int u32;

__device__ __forceinline__ float rcpf(float v) { return __builtin_amdgcn_rcpf(v); }
__device__ __forceinline__ float sigm(float v) { return rcpf(1.f + __expf(-v)); }
__device__ __forceinline__ float tanh_f(float v) {
  return fmaf(-2.f, rcpf(1.f + __expf(2.f * v)), 1.f);
}
__device__ __forceinline__ unsigned short f2bf(float f) {
  bf16 b = (bf16)f;
  return __builtin_bit_cast(unsigned short, b);
}
__device__ __forceinline__ u64 pload(const u64* p) {
  return __hip_atomic_load(p, __ATOMIC_RELAXED, __HIP_MEMORY_SCOPE_AGENT);
}
__device__ __forceinline__ void pstore(u64* p, u64 v) {
  __hip_atomic_store(p, v, __ATOMIC_RELAXED, __HIP_MEMORY_SCOPE_AGENT);
}
__device__ __forceinline__ u32 pload32(const u32* p) {
  return __hip_atomic_load(p, __ATOMIC_RELAXED, __HIP_MEMORY_SCOPE_AGENT);
}
__device__ __forceinline__ void pstore32(u32* p, u32 v) {
  __hip_atomic_store(p, v, __ATOMIC_RELAXED, __HIP_MEMORY_SCOPE_AGENT);
}

// Packet grid per h-matrix: p = m*256 + c, m=0..15 (rows m and m+16), c=0..255.
// payload: lo16 = row m, hi16 = row m+16, tag = high u32.

__device__ __forceinline__ void issue16(const u64* __restrict__ base, int tid, u64* v) {
#pragma unroll
  for (int i = 0; i < 16; ++i) v[i] = pload(base + (size_t)i * 256 + tid);
}
__device__ __forceinline__ void finish16(const u64* __restrict__ base, u32 want,
                                         int tid, u64* v) {
  u32 got = 0;
  for (;;) {
#pragma unroll
    for (int i = 0; i < 16; ++i)
      if (!(got & (1u << i)) && (u32)(v[i] >> 32) == want) got |= 1u << i;
    if (got == 0xFFFFu) return;
#pragma unroll
    for (int i = 0; i < 16; ++i)
      if (!(got & (1u << i))) v[i] = pload(base + (size_t)i * 256 + tid);
  }
}
// L2 foreign h2: 12 packets/thread over 192 foreign cols (coords in fm/fc)
__device__ __forceinline__ void issue12(const u64* __restrict__ base, const int* fm,
                                        const int* fc, u64* v) {
#pragma unroll
  for (int i = 0; i < 12; ++i) v[i] = pload(base + (size_t)fm[i] * 256 + fc[i]);
}
__device__ __forceinline__ void finish12_stage(const u64* __restrict__ base, u32 want,
                                               const int* fm, const int* fc,
                                               unsigned short (*hs)[kHP], u64* v) {
  u32 got = 0;
  for (;;) {
#pragma unroll
    for (int i = 0; i < 12; ++i) {
      if (!(got & (1u << i)) && (u32)(v[i] >> 32) == want) {
        got |= 1u << i;
        hs[fm[i]][fc[i]] = (unsigned short)v[i];
        hs[fm[i] + 16][fc[i]] = (unsigned short)(v[i] >> 16);
      }
    }
    if (got == 0xFFFu) return;
#pragma unroll
    for (int i = 0; i < 12; ++i)
      if (!(got & (1u << i))) v[i] = pload(base + (size_t)fm[i] * 256 + fc[i]);
  }
}
// L1 sibling half: 8 packets/thread over cols [pc0,pc0+128)
__device__ __forceinline__ void issue8h(const u64* __restrict__ base, int tid, int pc0,
                                        u64* v) {
  const int c = pc0 + (tid & 127), m0 = (tid >> 7) * 8;
#pragma unroll
  for (int i = 0; i < 8; ++i) v[i] = pload(base + (size_t)(m0 + i) * 256 + c);
}
__device__ __forceinline__ void finish8_stage(const u64* __restrict__ base, u32 want,
                                              int tid, int pc0,
                                              unsigned short (*hs)[kHP], u64* v) {
  const int c = pc0 + (tid & 127), m0 = (tid >> 7) * 8;
  u32 got = 0;
  for (;;) {
#pragma unroll
    for (int i = 0; i < 8; ++i) {
      if (!(got & (1u << i)) && (u32)(v[i] >> 32) == want) {
        got |= 1u << i;
        hs[m0 + i][c] = (unsigned short)v[i];
        hs[m0 + i + 16][c] = (unsigned short)(v[i] >> 16);
      }
    }
    if (got == 0xFFu) return;
#pragma unroll
    for (int i = 0; i < 8; ++i)
      if (!(got & (1u << i))) v[i] = pload(base + (size_t)(m0 + i) * 256 + c);
  }
}

// ---- convert + permute weights fp32 -> bf16 MFMA B-fragment order ----
__global__ __launch_bounds__(256) void k_convert(
    const float* __restrict__ wa, const float* __restrict__ wb, const float* __restrict__ wc,
    bf16* __restrict__ oa, bf16* __restrict__ ob, bf16* __restrict__ oc)
{
  const size_t total = (size_t)kN * 64 * 8 * 64;
  size_t gid = (size_t)blockIdx.x * 256 + threadIdx.x;
  if (gid >= total) return;
  const int lane = (int)(gid & 63);
  const int ks = (int)((gid >> 6) & 7);
  const int nt = (int)((gid >> 9) & 63);
  const int n = (int)(gid >> 15);
  const int g = nt * 16 + (lane & 15);
  const int k = ks * 32 + (lane >> 4) * 8;
  const size_t so = ((size_t)n * kG + g) * kH + k;

  const float4 a0 = *(const float4*)(wa + so), a1 = *(const float4*)(wa + so + 4);
  const float4 b0 = *(const float4*)(wb + so), b1 = *(const float4*)(wb + so + 4);
  const float4 c0 = *(const float4*)(wc + so), c1 = *(const float4*)(wc + so + 4);
  bf16x8 va, vb, vc;
  va[0]=(bf16)a0.x; va[1]=(bf16)a0.y; va[2]=(bf16)a0.z; va[3]=(bf16)a0.w;
  va[4]=(bf16)a1.x; va[5]=(bf16)a1.y; va[6]=(bf16)a1.z; va[7]=(bf16)a1.w;
  vb[0]=(bf16)b0.x; vb[1]=(bf16)b0.y; vb[2]=(bf16)b0.z; vb[3]=(bf16)b0.w;
  vb[4]=(bf16)b1.x; vb[5]=(bf16)b1.y; vb[6]=(bf16)b1.z; vb[7]=(bf16)b1.w;
  vc[0]=(bf16)c0.x; vc[1]=(bf16)c0.y; vc[2]=(bf16)c0.z; vc[3]=(bf16)c0.w;
  vc[4]=(bf16)c1.x; vc[5]=(bf16)c1.y; vc[6]=(bf16)c1.z; vc[7]=(bf16)c1.w;
  ((bf16x8*)oa)[gid] = va;
  ((bf16x8*)ob)[gid] = vb;
  ((bf16x8*)oc)[gid] = vc;
}

// MFMA over 4 K-slices [KS0, KS0+4) of hs1 against W (L1). KS0 must be a literal.
#define L1_MFMA_HALF(KS0)                                                            \
  _Pragma("unroll")                                                                  \
  for (int kk = 0; kk < 4; ++kk) {                                                   \
    const int ks = (KS0) + kk;                                                       \
    bf16x8 A0 = *(const bf16x8*)&hs1[l15][ks * 32 + l4 * 8];                         \
    bf16x8 A1 = *(const bf16x8*)&hs1[16 + l15][ks * 32 + l4 * 8];                    \
    _Pragma("unroll")                                                                \
    for (int jj = 0; jj < 2; ++jj)                                                   \
      _Pragma("unroll")                                                              \
      for (int gt = 0; gt < 4; ++gt) {                                               \
        acc[0][jj][gt] = __builtin_amdgcn_mfma_f32_16x16x32_bf16(                    \
            A0, W[jj][gt][ks], acc[0][jj][gt], 0, 0, 0);                             \
        acc[1][jj][gt] = __builtin_amdgcn_mfma_f32_16x16x32_bf16(                    \
            A1, W[jj][gt][ks], acc[1][jj][gt], 0, 0, 0);                             \
      }                                                                              \
  }

// ---- two concurrent recurrent chains ----
__global__ __launch_bounds__(256) __attribute__((amdgpu_waves_per_eu(1, 1)))
void k_lstm(
    const float* __restrict__ x, const float* __restrict__ Wih1,
    const float* __restrict__ bih1, const float* __restrict__ bhh1,
    const float* __restrict__ bih2, const float* __restrict__ bhh2,
    const bf16* __restrict__ pk1, const bf16* __restrict__ pk2i,
    const bf16* __restrict__ pk2h, float* __restrict__ h2_final,
    u64* __restrict__ h1r, u64* __restrict__ h2r, u32* __restrict__ prog)
{
  const int blk = blockIdx.x;
  const int tid = threadIdx.x, wv = tid >> 6, lane = tid & 63;
  const int l15 = lane & 15, l4 = lane >> 4;

  __shared__ alignas(16) unsigned short hs1[kB][kHP];

  if (blk < 72) {
    // ================= L1: h1 chain (identical to R11) ==========================
    const int n = blk >> 1, j = blk & 1;
    __shared__ float xsh[kT][kB];
    for (int i = tid; i < kB * kT; i += 256) {
      int b = i >> 7, t = i & 127;
      xsh[t][b] = x[((size_t)b * kT + t) * kN + n];
    }
    bf16x8 W[2][4][8]; // 256 VGPRs
    {
      const bf16x8* base = (const bf16x8*)pk1 + (size_t)n * 32768;
#pragma unroll
      for (int jj = 0; jj < 2; ++jj)
#pragma unroll
        for (int gt = 0; gt < 4; ++gt)
#pragma unroll
          for (int ks = 0; ks < 8; ++ks)
            W[jj][gt][ks] = base[(size_t)(gt * 16 + j * 8 + wv * 2 + jj) * 512 + ks * 64 + lane];
    }
    float wih[2][4], bg[2][4];
#pragma unroll
    for (int jj = 0; jj < 2; ++jj)
#pragma unroll
      for (int gt = 0; gt < 4; ++gt) {
        int g = gt * 256 + j * 128 + wv * 32 + jj * 16 + l15;
        wih[jj][gt] = Wih1[n * kG + g];
        bg[jj][gt] = bih1[n * kG + g] + bhh1[n * kG + g];
      }
    float cst[2][2][4];
#pragma unroll
    for (int a = 0; a < 2; ++a)
#pragma unroll
      for (int b = 0; b < 2; ++b)
#pragma unroll
        for (int r = 0; r < 4; ++r) cst[a][b][r] = 0.f;

    u64* ringn = h1r + (size_t)n * kD1 * 4096;
    u32* pg = prog + n * 4;
    const int pc0 = (1 - j) * 128, myb = j * 128 + wv * 32;
    u64 pv[8];
    __syncthreads();

#pragma unroll 1
    for (int t = 0; t < kT; ++t) {
      if ((t & 7) == 0 && t) { // ring back-pressure vs slowest L2 quarter
        if (tid == 0) {
          for (;;) {
            u32 m0 = pload32(&pg[0]), m1 = pload32(&pg[1]);
            u32 m2 = pload32(&pg[2]), m3 = pload32(&pg[3]);
            u32 mn = m0 < m1 ? m0 : m1;
            mn = mn < m2 ? mn : m2;
            mn = mn < m3 ? mn : m3;
            if ((int)mn + 8 >= t) break;
          }
        }
        __syncthreads();
      }
      f32x4 acc[2][2][4];
#pragma unroll
      for (int mt = 0; mt < 2; ++mt)
#pragma unroll
        for (int jj = 0; jj < 2; ++jj)
#pragma unroll
          for (int gt = 0; gt < 4; ++gt)
#pragma unroll
            for (int r = 0; r < 4; ++r)
              acc[mt][jj][gt][r] = xsh[t][mt * 16 + l4 * 4 + r] * wih[jj][gt] + bg[jj][gt];
      if (t > 0) {
        const u64* ps = ringn + (size_t)((t - 1) % kD1) * 4096;
        if (j == 0) { L1_MFMA_HALF(0) } else { L1_MFMA_HALF(4) }
        finish8_stage(ps, (u32)t, tid, pc0, hs1, pv);
        __syncthreads();
        if (j == 0) { L1_MFMA_HALF(4) } else { L1_MFMA_HALF(0) }
      }
      u64* pub = ringn + (size_t)(t % kD1) * 4096;
      const u64 tagw = ((u64)(u32)(t + 1)) << 32;
      float hv[2][2][4];
#pragma unroll
      for (int jj = 0; jj < 2; ++jj) {
#pragma unroll
        for (int mt = 0; mt < 2; ++mt)
#pragma unroll
          for (int r = 0; r < 4; ++r) {
            float cc = sigm(acc[mt][jj][1][r]) * cst[mt][jj][r]
                     + sigm(acc[mt][jj][0][r]) * tanh_f(acc[mt][jj][2][r]);
            cst[mt][jj][r] = cc;
            hv[mt][jj][r] = sigm(acc[mt][jj][3][r]) * tanh_f(cc);
          }
#pragma unroll
        for (int r = 0; r < 4; ++r) {
          int c = myb + jj * 16 + l15, m = l4 * 4 + r;
          pstore(&pub[(size_t)m * 256 + c],
                 tagw | ((u64)f2bf(hv[1][jj][r]) << 16) | f2bf(hv[0][jj][r]));
        }
      }
#pragma unroll
      for (int mt = 0; mt < 2; ++mt)
#pragma unroll
        for (int jj = 0; jj < 2; ++jj)
#pragma unroll
          for (int r = 0; r < 4; ++r)
            hs1[mt * 16 + l4 * 4 + r][myb + jj * 16 + l15] = f2bf(hv[mt][jj][r]);
      if (t + 1 < kT) issue8h(pub, tid, pc0, pv);
      __syncthreads();
    }
  } else {
    // ====== L2: h2 chain; WG q owns cols [q*64,(q+1)*64); own-K-first ===========
    const int bb = blk - 72, n = bb >> 2, q = bb & 3;
    __shared__ alignas(16) unsigned short hs2[kB][kHP];

    bf16x8 Wi[4][8], Wh[4][8]; // 128 + 128 VGPRs; Wh ROTATED: slot i = ks (2q+i)&7
    {
      const bf16x8* bi = (const bf16x8*)pk2i + (size_t)n * 32768;
      const bf16x8* bh = (const bf16x8*)pk2h + (size_t)n * 32768;
#pragma unroll
      for (int gt = 0; gt < 4; ++gt)
#pragma unroll
        for (int i = 0; i < 8; ++i) {
          size_t nt = (size_t)(gt * 16 + q * 4 + wv) * 512;
          Wi[gt][i] = bi[nt + (size_t)i * 64 + lane];
          Wh[gt][i] = bh[nt + (size_t)((2 * q + i) & 7) * 64 + lane];
        }
    }
    int cb[8]; // rotated hs2 col base per slot
#pragma unroll
    for (int i = 0; i < 8; ++i) cb[i] = ((2 * q + i) & 7) * 32;
    // foreign packet coords: 192 cols not owned by q, 12 per thread
    int fm[12], fc[12];
#pragma unroll
    for (int i = 0; i < 12; ++i) {
      int p = tid * 12 + i;            // 0..3071
      int m = p / 192;
      fm[i] = m;
      fc[i] = (q * 64 + 64 + (p - m * 192)) & 255;
    }
    const int col = q * 64 + wv * 16 + l15;
    float bg[4];
#pragma unroll
    for (int gt = 0; gt < 4; ++gt) {
      int g = gt * 256 + col;
      bg[gt] = bih2[n * kG + g] + bhh2[n * kG + g];
    }
    float cst[2][4];
#pragma unroll
    for (int mt = 0; mt < 2; ++mt)
#pragma unroll
      for (int r = 0; r < 4; ++r) cst[mt][r] = 0.f;

    u64* ringn = h1r + (size_t)n * kD1 * 4096;
    u64* h2n = h2r + (size_t)n * 2 * 4096;
    u32* pg = prog + n * 4 + q;
    __syncthreads();

    // prologue: h1(0) (slot 0, tag 1) into regs + hs1
    u64 v1[16], v2[12];
    issue16(ringn, tid, v1);
    finish16(ringn, 1u, tid, v1);
#pragma unroll
    for (int i = 0; i < 16; ++i) {
      hs1[i][tid] = (unsigned short)v1[i];
      hs1[i + 16][tid] = (unsigned short)(v1[i] >> 16);
    }
    __syncthreads();

#pragma unroll 1
    for (int t = 0; t < kT; ++t) {
      if (tid == 0) pstore32(pg, (u32)(t + 1)); // h1(t) staged; ring slot reusable
      const u64* pn = ringn + (size_t)((t + 1) % kD1) * 4096;
      if (t + 1 < kT) issue16(pn, tid, v1);     // h1(t+1) prefetch
      // (C) u = Wih2 * h1(t) + bg2 (hs1 staged at prev tail; foreign h2 in flight)
      f32x4 acc[2][4];
#pragma unroll
      for (int mt = 0; mt < 2; ++mt)
#pragma unroll
        for (int gt = 0; gt < 4; ++gt)
#pragma unroll
          for (int r = 0; r < 4; ++r) acc[mt][gt][r] = bg[gt];
#pragma unroll
      for (int ks = 0; ks < 8; ++ks) {
        bf16x8 A0 = *(const bf16x8*)&hs1[l15][ks * 32 + l4 * 8];
        bf16x8 A1 = *(const bf16x8*)&hs1[16 + l15][ks * 32 + l4 * 8];
#pragma unroll
        for (int gt = 0; gt < 4; ++gt) {
          acc[0][gt] = __builtin_amdgcn_mfma_f32_16x16x32_bf16(A0, Wi[gt][ks], acc[0][gt], 0, 0, 0);
          acc[1][gt] = __builtin_amdgcn_mfma_f32_16x16x32_bf16(A1, Wi[gt][ks], acc[1][gt], 0, 0, 0);
        }
      }
      if (t > 0) {
        // (C2) own-K Whh2 (slots 0,1): own cols written to hs2 at prev publish
#pragma unroll
        for (int i = 0; i < 2; ++i) {
          bf16x8 A0 = *(const bf16x8*)&hs2[l15][cb[i] + l4 * 8];
          bf16x8 A1 = *(const bf16x8*)&hs2[16 + l15][cb[i] + l4 * 8];
#pragma unroll
          for (int gt = 0; gt < 4; ++gt) {
            acc[0][gt] = __builtin_amdgcn_mfma_f32_16x16x32_bf16(A0, Wh[gt][i], acc[0][gt], 0, 0, 0);
            acc[1][gt] = __builtin_amdgcn_mfma_f32_16x16x32_bf16(A1, Wh[gt][i], acc[1][gt], 0, 0, 0);
          }
        }
        // (D) foreign h2(t-1): validate + stage (loads issued at prev step's tail)
        finish12_stage(h2n + (size_t)((t - 1) & 1) * 4096, (u32)t, fm, fc, hs2, v2);
        __syncthreads();
#pragma unroll
        for (int i = 2; i < 8; ++i) {
          bf16x8 A0 = *(const bf16x8*)&hs2[l15][cb[i] + l4 * 8];
          bf16x8 A1 = *(const bf16x8*)&hs2[16 + l15][cb[i] + l4 * 8];
#pragma unroll
          for (int gt = 0; gt < 4; ++gt) {
            acc[0][gt] = __builtin_amdgcn_mfma_f32_16x16x32_bf16(A0, Wh[gt][i], acc[0][gt], 0, 0, 0);
            acc[1][gt] = __builtin_amdgcn_mfma_f32_16x16x32_bf16(A1, Wh[gt][i], acc[1][gt], 0, 0, 0);
          }
        }
      } else {
        __syncthreads(); // t=0: keep hs1 readers/writers separated uniformly
      }
      // (E) cell + publish + own hs2 write, interleaved per r
      u64* pub = h2n + (size_t)(t & 1) * 4096;
      const u64 tagw = ((u64)(u32)(t + 1)) << 32;
      float hv[2][4];
#pragma unroll
      for (int r = 0; r < 4; ++r) {
#pragma unroll
        for (int mt = 0; mt < 2; ++mt) {
          float cc = sigm(acc[mt][1][r]) * cst[mt][r]
                   + sigm(acc[mt][0][r]) * tanh_f(acc[mt][2][r]);
          cst[mt][r] = cc;
          hv[mt][r] = sigm(acc[mt][3][r]) * tanh_f(cc);
        }
        pstore(&pub[(size_t)(l4 * 4 + r) * 256 + col],
               tagw | ((u64)f2bf(hv[1][r]) << 16) | f2bf(hv[0][r]));
        hs2[l4 * 4 + r][col] = f2bf(hv[0][r]);      // own cols for next own-K
        hs2[l4 * 4 + r + 16][col] = f2bf(hv[1][r]);
      }
      if (t == kT - 1) {
#pragma unroll
        for (int mt = 0; mt < 2; ++mt)
#pragma unroll
          for (int r = 0; r < 4; ++r)
            h2_final[((size_t)n * kB + (mt * 16 + l4 * 4 + r)) * kH + col] = hv[mt][r];
      }
      if (t + 1 < kT) issue12(pub, fm, fc, v2); // early-issue next foreign h2
      // tail: finish + stage h1(t+1) (prefetch-hit), then single barrier
      if (t + 1 < kT) {
        finish16(pn, (u32)(t + 2), tid, v1);
#pragma unroll
        for (int i = 0; i < 16; ++i) {
          hs1[i][tid] = (unsigned short)v1[i];
          hs1[i + 16][tid] = (unsigned short)(v1[i] >> 16);
        }
      }
      __syncthreads();
    }
  }
}

// ---- head ----
__global__ __launch_bounds__(256) void k_head1(
    const float* __restrict__ spec, const float* __restrict__ Wspec,
    const float* __restrict__ bspec, const float* __restrict__ Wp1,
    const float* __restrict__ h2f, float* __restrict__ partial)
{
  const int kc = blockIdx.x;
  const int b = blockIdx.y;
  const int o = threadIdx.x;
  __shared__ float fs[kH];
  if (kc < kN) {
    fs[o] = h2f[((size_t)kc * kB + b) * kH + o];
  } else {
    float v = bspec[o];
#pragma unroll
    for (int s = 0; s < kSpec; ++s) v += spec[b * kSpec + s] * Wspec[s * kH + o];
    fs[o] = v;
  }
  __syncthreads();
  const float* __restrict__ wp = Wp1 + (size_t)kc * 256 * kH + o;
  float a = 0.f;
#pragma unroll 8
  for (int i = 0; i < 256; ++i) a += fs[i] * wp[(size_t)i * kH];
  partial[((size_t)kc * kB + b) * kH + o] = a;
}

__global__ __launch_bounds__(256) void k_head2(
    const float* __restrict__ bp1, const float* __restrict__ Wp2,
    const float* __restrict__ bp2, const float* __restrict__ partial,
    float* __restrict__ out)
{
  const int b = blockIdx.x;
  const int o = threadIdx.x;
  __shared__ float hid[kH];
  float a = bp1[o];
#pragma unroll
  for (int kc = 0; kc < kN + 1; ++kc) a += partial[((size_t)kc * kB + b) * kH + o];
  hid[o] = fmaxf(a, 0.f);
  __syncthreads();
  if (o < kOut) {
    float r = bp2[o];
#pragma unroll 8
    for (int h = 0; h < kH; ++h) r += hid[h] * Wp2[h * kOut + o];
    out[b * kOut + o] = r;
  }
}

extern "C" void kernel_launch(void* const* d_in, const int* in_sizes, int n_in,
                              void* d_out, int out_size, void* d_ws, size_t ws_size,
                              hipStream_t stream) {
  const float* x = (const float*)d_in[0];
  const float* spec = (const float*)d_in[1];
  const float* Wih1 = (const float*)d_in[2];
  const float* Whh1 = (const float*)d_in[3];
  const float* bih1 = (const float*)d_in[4];
  const float* bhh1 = (const float*)d_in[5];
  const float* Wih2 = (const float*)d_in[6];
  const float* Whh2 = (const float*)d_in[7];
  const float* bih2 = (const float*)d_in[8];
  const float* bhh2 = (const float*)d_in[9];
  const float* Wspec = (const float*)d_in[10];
  const float* bspec = (const float*)d_in[11];
  const float* Wp1 = (const float*)d_in[12];
  const float* bp1 = (const float*)d_in[13];
  const float* Wp2 = (const float*)d_in[14];
  const float* bp2 = (const float*)d_in[15];
  float* out = (float*)d_out;

  // ws (~80 MB): [prog 4K][h1r 18.9M][h2r 2.4M][pk1|pk2i|pk2h 56.6M][h2_final][partial]
  // Only prog is memset; tagged rings are self-validating (stale tags never match).
  const size_t WSZ = (size_t)kN * kG * kH;
  u32* prog = (u32*)d_ws;
  u64* h1r = (u64*)((char*)d_ws + 4096);                    // 36*16*4096 u64 = 18.87 MB
  u64* h2r = h1r + (size_t)kN * kD1 * 4096;                 // 36*2*4096 u64 = 2.36 MB
  bf16* pk1 = (bf16*)(h2r + (size_t)kN * 2 * 4096);
  bf16* pk2i = pk1 + WSZ;
  bf16* pk2h = pk2i + WSZ;
  float* h2_final = (float*)(pk2h + WSZ);
  float* partial = h2_final + (size_t)kN * kB * kH;

  hipMemsetAsync(d_ws, 0, 4096, stream); // progress counters only

  const size_t groups = (size_t)kN * 64 * 8 * 64;
  k_convert<<<dim3((unsigned)((groups + 255) / 256)), dim3(256), 0, stream>>>(
      Whh1, Wih2, Whh2, pk1, pk2i, pk2h);
  k_lstm<<<dim3(216), dim3(256), 0, stream>>>(
      x, Wih1, bih1, bhh1, bih2, bhh2, pk1, pk2i, pk2h, h2_final, h1r, h2r, prog);
  k_head1<<<dim3(kN + 1, kB), dim3(256), 0, stream>>>(spec, Wspec, bspec, Wp1, h2_final, partial);
  k_head2<<<dim3(kB), dim3(256), 0, stream>>>(bp1, Wp2, bp2, partial, out);
}

// Round 7
// 1004.892 us; speedup vs baseline: 1.8690x; 1.8690x over previous
//
#include <hip/hip_runtime.h>
#include <cstdint>
#include <cstddef>

// LSTMClassifier R13: R11 base (proven 875us) + own-K-first Whh2 done SAFELY.
// R12 post-mortem: 2x regression from switching the foreign poll to a scattered
// per-thread pattern (64 lines/instr vs 8); MfmaUtil*dur conserved across R6-R12
// (~9400) -> clock constant, cycles doubled = pure added wait. Lesson: never touch
// the (coalesced) poll access pattern, only its position.
// R13 L2 changes vs R11 (poll pattern IDENTICAL):
//  - own h2 cols written to LDS hs2 at publish time (8 ds_writes, cheap);
//  - Wh registers loaded ROTATED by 2q: slot i holds ks=(2q+i)&7, so own K-slots
//    are compile-time i=0,1 (no runtime-indexed reg arrays -> no scratch);
//  - step order: Wih2(8ks) -> own-K Whh2(i=0,1, LDS-local) -> finish16_stage(full
//    256-col coalesced poll, unchanged) -> barrier -> foreign Whh2(i=2..7).
//  Post-detect tail: 48 MFMA + cell (was 64 MFMA + cell); ~500cy more arrival
//  headroom before the wait. Staging re-writes own cols with identical bf16 bits
//  (benign race). L1 kept EXACTLY R11.

constexpr int kN = 36, kH = 256, kG = 1024, kB = 32, kT = 128, kSpec = 6, kOut = 30;
constexpr int kHP = 264;   // LDS h stride (ushort)
constexpr int kD1 = 16;    // h1 ring depth (steps)

typedef __bf16 bf16;
typedef __bf16 bf16x8 __attribute__((ext_vector_type(8)));
typedef float f32x4 __attribute__((ext_vector_type(4)));
typedef unsigned long long u64;
typedef unsigned int u32;

__device__ __forceinline__ float rcpf(float v) { return __builtin_amdgcn_rcpf(v); }
__device__ __forceinline__ float sigm(float v) { return rcpf(1.f + __expf(-v)); }
__device__ __forceinline__ float tanh_f(float v) {
  return fmaf(-2.f, rcpf(1.f + __expf(2.f * v)), 1.f);
}
__device__ __forceinline__ unsigned short f2bf(float f) {
  bf16 b = (bf16)f;
  return __builtin_bit_cast(unsigned short, b);
}
__device__ __forceinline__ u64 pload(const u64* p) {
  return __hip_atomic_load(p, __ATOMIC_RELAXED, __HIP_MEMORY_SCOPE_AGENT);
}
__device__ __forceinline__ void pstore(u64* p, u64 v) {
  __hip_atomic_store(p, v, __ATOMIC_RELAXED, __HIP_MEMORY_SCOPE_AGENT);
}
__device__ __forceinline__ u32 pload32(const u32* p) {
  return __hip_atomic_load(p, __ATOMIC_RELAXED, __HIP_MEMORY_SCOPE_AGENT);
}
__device__ __forceinline__ void pstore32(u32* p, u32 v) {
  __hip_atomic_store(p, v, __ATOMIC_RELAXED, __HIP_MEMORY_SCOPE_AGENT);
}

// Packet grid per h-matrix: p = m*256 + c, m=0..15 (rows m and m+16), c=0..255.
// payload: lo16 = row m, hi16 = row m+16, tag = high u32.

__device__ __forceinline__ void issue16(const u64* __restrict__ base, int tid, u64* v) {
#pragma unroll
  for (int i = 0; i < 16; ++i) v[i] = pload(base + (size_t)i * 256 + tid);
}
__device__ __forceinline__ void finish16(const u64* __restrict__ base, u32 want,
                                         int tid, u64* v) {
  u32 got = 0;
  for (;;) {
#pragma unroll
    for (int i = 0; i < 16; ++i)
      if (!(got & (1u << i)) && (u32)(v[i] >> 32) == want) got |= 1u << i;
    if (got == 0xFFFFu) return;
#pragma unroll
    for (int i = 0; i < 16; ++i)
      if (!(got & (1u << i))) v[i] = pload(base + (size_t)i * 256 + tid);
  }
}
__device__ __forceinline__ void finish16_stage(const u64* __restrict__ base, u32 want,
                                               int tid, unsigned short (*hs)[kHP],
                                               u64* v) {
  u32 got = 0;
  for (;;) {
#pragma unroll
    for (int i = 0; i < 16; ++i) {
      if (!(got & (1u << i)) && (u32)(v[i] >> 32) == want) {
        got |= 1u << i;
        hs[i][tid] = (unsigned short)v[i];
        hs[i + 16][tid] = (unsigned short)(v[i] >> 16);
      }
    }
    if (got == 0xFFFFu) return;
#pragma unroll
    for (int i = 0; i < 16; ++i)
      if (!(got & (1u << i))) v[i] = pload(base + (size_t)i * 256 + tid);
  }
}
// L1 sibling half: 8 packets/thread over cols [pc0,pc0+128)
__device__ __forceinline__ void issue8h(const u64* __restrict__ base, int tid, int pc0,
                                        u64* v) {
  const int c = pc0 + (tid & 127), m0 = (tid >> 7) * 8;
#pragma unroll
  for (int i = 0; i < 8; ++i) v[i] = pload(base + (size_t)(m0 + i) * 256 + c);
}
__device__ __forceinline__ void finish8_stage(const u64* __restrict__ base, u32 want,
                                              int tid, int pc0,
                                              unsigned short (*hs)[kHP], u64* v) {
  const int c = pc0 + (tid & 127), m0 = (tid >> 7) * 8;
  u32 got = 0;
  for (;;) {
#pragma unroll
    for (int i = 0; i < 8; ++i) {
      if (!(got & (1u << i)) && (u32)(v[i] >> 32) == want) {
        got |= 1u << i;
        hs[m0 + i][c] = (unsigned short)v[i];
        hs[m0 + i + 16][c] = (unsigned short)(v[i] >> 16);
      }
    }
    if (got == 0xFFu) return;
#pragma unroll
    for (int i = 0; i < 8; ++i)
      if (!(got & (1u << i))) v[i] = pload(base + (size_t)(m0 + i) * 256 + c);
  }
}

// ---- convert + permute weights fp32 -> bf16 MFMA B-fragment order ----
__global__ __launch_bounds__(256) void k_convert(
    const float* __restrict__ wa, const float* __restrict__ wb, const float* __restrict__ wc,
    bf16* __restrict__ oa, bf16* __restrict__ ob, bf16* __restrict__ oc)
{
  const size_t total = (size_t)kN * 64 * 8 * 64;
  size_t gid = (size_t)blockIdx.x * 256 + threadIdx.x;
  if (gid >= total) return;
  const int lane = (int)(gid & 63);
  const int ks = (int)((gid >> 6) & 7);
  const int nt = (int)((gid >> 9) & 63);
  const int n = (int)(gid >> 15);
  const int g = nt * 16 + (lane & 15);
  const int k = ks * 32 + (lane >> 4) * 8;
  const size_t so = ((size_t)n * kG + g) * kH + k;

  const float4 a0 = *(const float4*)(wa + so), a1 = *(const float4*)(wa + so + 4);
  const float4 b0 = *(const float4*)(wb + so), b1 = *(const float4*)(wb + so + 4);
  const float4 c0 = *(const float4*)(wc + so), c1 = *(const float4*)(wc + so + 4);
  bf16x8 va, vb, vc;
  va[0]=(bf16)a0.x; va[1]=(bf16)a0.y; va[2]=(bf16)a0.z; va[3]=(bf16)a0.w;
  va[4]=(bf16)a1.x; va[5]=(bf16)a1.y; va[6]=(bf16)a1.z; va[7]=(bf16)a1.w;
  vb[0]=(bf16)b0.x; vb[1]=(bf16)b0.y; vb[2]=(bf16)b0.z; vb[3]=(bf16)b0.w;
  vb[4]=(bf16)b1.x; vb[5]=(bf16)b1.y; vb[6]=(bf16)b1.z; vb[7]=(bf16)b1.w;
  vc[0]=(bf16)c0.x; vc[1]=(bf16)c0.y; vc[2]=(bf16)c0.z; vc[3]=(bf16)c0.w;
  vc[4]=(bf16)c1.x; vc[5]=(bf16)c1.y; vc[6]=(bf16)c1.z; vc[7]=(bf16)c1.w;
  ((bf16x8*)oa)[gid] = va;
  ((bf16x8*)ob)[gid] = vb;
  ((bf16x8*)oc)[gid] = vc;
}

// MFMA over 4 K-slices [KS0, KS0+4) of hs1 against W (L1). KS0 must be a literal.
#define L1_MFMA_HALF(KS0)                                                            \
  _Pragma("unroll")                                                                  \
  for (int kk = 0; kk < 4; ++kk) {                                                   \
    const int ks = (KS0) + kk;                                                       \
    bf16x8 A0 = *(const bf16x8*)&hs1[l15][ks * 32 + l4 * 8];                         \
    bf16x8 A1 = *(const bf16x8*)&hs1[16 + l15][ks * 32 + l4 * 8];                    \
    _Pragma("unroll")                                                                \
    for (int jj = 0; jj < 2; ++jj)                                                   \
      _Pragma("unroll")                                                              \
      for (int gt = 0; gt < 4; ++gt) {                                               \
        acc[0][jj][gt] = __builtin_amdgcn_mfma_f32_16x16x32_bf16(                    \
            A0, W[jj][gt][ks], acc[0][jj][gt], 0, 0, 0);                             \
        acc[1][jj][gt] = __builtin_amdgcn_mfma_f32_16x16x32_bf16(                    \
            A1, W[jj][gt][ks], acc[1][jj][gt], 0, 0, 0);                             \
      }                                                                              \
  }

// ---- two concurrent recurrent chains ----
__global__ __launch_bounds__(256) __attribute__((amdgpu_waves_per_eu(1, 1)))
void k_lstm(
    const float* __restrict__ x, const float* __restrict__ Wih1,
    const float* __restrict__ bih1, const float* __restrict__ bhh1,
    const float* __restrict__ bih2, const float* __restrict__ bhh2,
    const bf16* __restrict__ pk1, const bf16* __restrict__ pk2i,
    const bf16* __restrict__ pk2h, float* __restrict__ h2_final,
    u64* __restrict__ h1r, u64* __restrict__ h2r, u32* __restrict__ prog)
{
  const int blk = blockIdx.x;
  const int tid = threadIdx.x, wv = tid >> 6, lane = tid & 63;
  const int l15 = lane & 15, l4 = lane >> 4;

  __shared__ alignas(16) unsigned short hs1[kB][kHP];

  if (blk < 72) {
    // ================= L1: h1 chain (identical to R11) ==========================
    const int n = blk >> 1, j = blk & 1;
    __shared__ float xsh[kT][kB];
    for (int i = tid; i < kB * kT; i += 256) {
      int b = i >> 7, t = i & 127;
      xsh[t][b] = x[((size_t)b * kT + t) * kN + n];
    }
    bf16x8 W[2][4][8]; // 256 VGPRs
    {
      const bf16x8* base = (const bf16x8*)pk1 + (size_t)n * 32768;
#pragma unroll
      for (int jj = 0; jj < 2; ++jj)
#pragma unroll
        for (int gt = 0; gt < 4; ++gt)
#pragma unroll
          for (int ks = 0; ks < 8; ++ks)
            W[jj][gt][ks] = base[(size_t)(gt * 16 + j * 8 + wv * 2 + jj) * 512 + ks * 64 + lane];
    }
    float wih[2][4], bg[2][4];
#pragma unroll
    for (int jj = 0; jj < 2; ++jj)
#pragma unroll
      for (int gt = 0; gt < 4; ++gt) {
        int g = gt * 256 + j * 128 + wv * 32 + jj * 16 + l15;
        wih[jj][gt] = Wih1[n * kG + g];
        bg[jj][gt] = bih1[n * kG + g] + bhh1[n * kG + g];
      }
    float cst[2][2][4];
#pragma unroll
    for (int a = 0; a < 2; ++a)
#pragma unroll
      for (int b = 0; b < 2; ++b)
#pragma unroll
        for (int r = 0; r < 4; ++r) cst[a][b][r] = 0.f;

    u64* ringn = h1r + (size_t)n * kD1 * 4096;
    u32* pg = prog + n * 4;
    const int pc0 = (1 - j) * 128, myb = j * 128 + wv * 32;
    u64 pv[8];
    __syncthreads();

#pragma unroll 1
    for (int t = 0; t < kT; ++t) {
      if ((t & 7) == 0 && t) { // ring back-pressure vs slowest L2 quarter
        if (tid == 0) {
          for (;;) {
            u32 m0 = pload32(&pg[0]), m1 = pload32(&pg[1]);
            u32 m2 = pload32(&pg[2]), m3 = pload32(&pg[3]);
            u32 mn = m0 < m1 ? m0 : m1;
            mn = mn < m2 ? mn : m2;
            mn = mn < m3 ? mn : m3;
            if ((int)mn + 8 >= t) break;
          }
        }
        __syncthreads();
      }
      f32x4 acc[2][2][4];
#pragma unroll
      for (int mt = 0; mt < 2; ++mt)
#pragma unroll
        for (int jj = 0; jj < 2; ++jj)
#pragma unroll
          for (int gt = 0; gt < 4; ++gt)
#pragma unroll
            for (int r = 0; r < 4; ++r)
              acc[mt][jj][gt][r] = xsh[t][mt * 16 + l4 * 4 + r] * wih[jj][gt] + bg[jj][gt];
      if (t > 0) {
        const u64* ps = ringn + (size_t)((t - 1) % kD1) * 4096;
        if (j == 0) { L1_MFMA_HALF(0) } else { L1_MFMA_HALF(4) }
        finish8_stage(ps, (u32)t, tid, pc0, hs1, pv);
        __syncthreads();
        if (j == 0) { L1_MFMA_HALF(4) } else { L1_MFMA_HALF(0) }
      }
      u64* pub = ringn + (size_t)(t % kD1) * 4096;
      const u64 tagw = ((u64)(u32)(t + 1)) << 32;
      float hv[2][2][4];
#pragma unroll
      for (int jj = 0; jj < 2; ++jj) {
#pragma unroll
        for (int mt = 0; mt < 2; ++mt)
#pragma unroll
          for (int r = 0; r < 4; ++r) {
            float cc = sigm(acc[mt][jj][1][r]) * cst[mt][jj][r]
                     + sigm(acc[mt][jj][0][r]) * tanh_f(acc[mt][jj][2][r]);
            cst[mt][jj][r] = cc;
            hv[mt][jj][r] = sigm(acc[mt][jj][3][r]) * tanh_f(cc);
          }
#pragma unroll
        for (int r = 0; r < 4; ++r) {
          int c = myb + jj * 16 + l15, m = l4 * 4 + r;
          pstore(&pub[(size_t)m * 256 + c],
                 tagw | ((u64)f2bf(hv[1][jj][r]) << 16) | f2bf(hv[0][jj][r]));
        }
      }
#pragma unroll
      for (int mt = 0; mt < 2; ++mt)
#pragma unroll
        for (int jj = 0; jj < 2; ++jj)
#pragma unroll
          for (int r = 0; r < 4; ++r)
            hs1[mt * 16 + l4 * 4 + r][myb + jj * 16 + l15] = f2bf(hv[mt][jj][r]);
      if (t + 1 < kT) issue8h(pub, tid, pc0, pv);
      __syncthreads();
    }
  } else {
    // ====== L2: h2 chain; WG q owns cols [q*64,(q+1)*64); own-K-first ===========
    const int bb = blk - 72, n = bb >> 2, q = bb & 3;
    __shared__ alignas(16) unsigned short hs2[kB][kHP];

    bf16x8 Wi[4][8], Wh[4][8]; // Wh ROTATED: slot i holds ks=(2q+i)&7; own = i 0,1
    {
      const bf16x8* bi = (const bf16x8*)pk2i + (size_t)n * 32768;
      const bf16x8* bh = (const bf16x8*)pk2h + (size_t)n * 32768;
#pragma unroll
      for (int gt = 0; gt < 4; ++gt)
#pragma unroll
        for (int i = 0; i < 8; ++i) {
          size_t nt = (size_t)(gt * 16 + q * 4 + wv) * 512;
          Wi[gt][i] = bi[nt + (size_t)i * 64 + lane];
          Wh[gt][i] = bh[nt + (size_t)((2 * q + i) & 7) * 64 + lane];
        }
    }
    int cb[8]; // hs2 col base per rotated slot
#pragma unroll
    for (int i = 0; i < 8; ++i) cb[i] = ((2 * q + i) & 7) * 32;
    const int col = q * 64 + wv * 16 + l15;
    float bg[4];
#pragma unroll
    for (int gt = 0; gt < 4; ++gt) {
      int g = gt * 256 + col;
      bg[gt] = bih2[n * kG + g] + bhh2[n * kG + g];
    }
    float cst[2][4];
#pragma unroll
    for (int mt = 0; mt < 2; ++mt)
#pragma unroll
      for (int r = 0; r < 4; ++r) cst[mt][r] = 0.f;

    u64* ringn = h1r + (size_t)n * kD1 * 4096;
    u64* h2n = h2r + (size_t)n * 2 * 4096;
    u32* pg = prog + n * 4 + q;
    __syncthreads();

    // prologue: h1(0), ring slot 0, tag 1
    u64 v1[16], v2[16];
    issue16(ringn, tid, v1);
    finish16(ringn, 1u, tid, v1);

#pragma unroll 1
    for (int t = 0; t < kT; ++t) {
      // (A) stage prefetched h1(t) into hs1
#pragma unroll
      for (int i = 0; i < 16; ++i) {
        hs1[i][tid] = (unsigned short)v1[i];
        hs1[i + 16][tid] = (unsigned short)(v1[i] >> 16);
      }
      __syncthreads();
      if (tid == 0) pstore32(pg, (u32)(t + 1)); // h1(t) consumed; ring slot reusable
      // (B) fire h1(t+1) prefetch; h2(t-1) loads were issued at END of step t-1
      const u64* pn = ringn + (size_t)((t + 1) % kD1) * 4096;
      if (t + 1 < kT) issue16(pn, tid, v1);
      // (C) u = Wih2 * h1(t) + bg2 (h2 propagate hidden under A+B+C+C2)
      f32x4 acc[2][4];
#pragma unroll
      for (int mt = 0; mt < 2; ++mt)
#pragma unroll
        for (int gt = 0; gt < 4; ++gt)
#pragma unroll
          for (int r = 0; r < 4; ++r) acc[mt][gt][r] = bg[gt];
#pragma unroll
      for (int ks = 0; ks < 8; ++ks) {
        bf16x8 A0 = *(const bf16x8*)&hs1[l15][ks * 32 + l4 * 8];
        bf16x8 A1 = *(const bf16x8*)&hs1[16 + l15][ks * 32 + l4 * 8];
#pragma unroll
        for (int gt = 0; gt < 4; ++gt) {
          acc[0][gt] = __builtin_amdgcn_mfma_f32_16x16x32_bf16(A0, Wi[gt][ks], acc[0][gt], 0, 0, 0);
          acc[1][gt] = __builtin_amdgcn_mfma_f32_16x16x32_bf16(A1, Wi[gt][ks], acc[1][gt], 0, 0, 0);
        }
      }
      if (t > 0) {
        // (C2) own-K Whh2 (rotated slots 0,1): own cols written to hs2 at prev (E).
        // Other waves may be re-staging identical bits in (D) concurrently - benign.
#pragma unroll
        for (int i = 0; i < 2; ++i) {
          bf16x8 A0 = *(const bf16x8*)&hs2[l15][cb[i] + l4 * 8];
          bf16x8 A1 = *(const bf16x8*)&hs2[16 + l15][cb[i] + l4 * 8];
#pragma unroll
          for (int gt = 0; gt < 4; ++gt) {
            acc[0][gt] = __builtin_amdgcn_mfma_f32_16x16x32_bf16(A0, Wh[gt][i], acc[0][gt], 0, 0, 0);
            acc[1][gt] = __builtin_amdgcn_mfma_f32_16x16x32_bf16(A1, Wh[gt][i], acc[1][gt], 0, 0, 0);
          }
        }
        // (D) h2(t-1): validate + stage (R11's coalesced full-256-col pattern)
        finish16_stage(h2n + (size_t)((t - 1) & 1) * 4096, (u32)t, tid, hs2, v2);
        __syncthreads();
        // foreign Whh2 (rotated slots 2..7)
#pragma unroll
        for (int i = 2; i < 8; ++i) {
          bf16x8 A0 = *(const bf16x8*)&hs2[l15][cb[i] + l4 * 8];
          bf16x8 A1 = *(const bf16x8*)&hs2[16 + l15][cb[i] + l4 * 8];
#pragma unroll
          for (int gt = 0; gt < 4; ++gt) {
            acc[0][gt] = __builtin_amdgcn_mfma_f32_16x16x32_bf16(A0, Wh[gt][i], acc[0][gt], 0, 0, 0);
            acc[1][gt] = __builtin_amdgcn_mfma_f32_16x16x32_bf16(A1, Wh[gt][i], acc[1][gt], 0, 0, 0);
          }
        }
      }
      // (E) cell + publish + own hs2 LDS write, interleaved per r
      u64* pub = h2n + (size_t)(t & 1) * 4096;
      const u64 tagw = ((u64)(u32)(t + 1)) << 32;
      float hv[2][4];
#pragma unroll
      for (int r = 0; r < 4; ++r) {
#pragma unroll
        for (int mt = 0; mt < 2; ++mt) {
          float cc = sigm(acc[mt][1][r]) * cst[mt][r]
                   + sigm(acc[mt][0][r]) * tanh_f(acc[mt][2][r]);
          cst[mt][r] = cc;
          hv[mt][r] = sigm(acc[mt][3][r]) * tanh_f(cc);
        }
        pstore(&pub[(size_t)(l4 * 4 + r) * 256 + col],
               tagw | ((u64)f2bf(hv[1][r]) << 16) | f2bf(hv[0][r]));
        hs2[l4 * 4 + r][col] = f2bf(hv[0][r]);      // own cols for next own-K
        hs2[l4 * 4 + r + 16][col] = f2bf(hv[1][r]);
      }
      if (t == kT - 1) {
#pragma unroll
        for (int mt = 0; mt < 2; ++mt)
#pragma unroll
          for (int r = 0; r < 4; ++r)
            h2_final[((size_t)n * kB + (mt * 16 + l4 * 4 + r)) * kH + col] = hv[mt][r];
      }
      // (E2) early-issue next h2 (all 256 cols; coalesced pattern unchanged)
      if (t + 1 < kT) issue16(pub, tid, v2);
      // (F) validate h1(t+1) prefetch (usually already arrived)
      if (t + 1 < kT) finish16(pn, (u32)(t + 2), tid, v1);
      __syncthreads(); // all MFMA/LDS reads done before next (A)/(C2)
    }
  }
}

// ---- head ----
__global__ __launch_bounds__(256) void k_head1(
    const float* __restrict__ spec, const float* __restrict__ Wspec,
    const float* __restrict__ bspec, const float* __restrict__ Wp1,
    const float* __restrict__ h2f, float* __restrict__ partial)
{
  const int kc = blockIdx.x;
  const int b = blockIdx.y;
  const int o = threadIdx.x;
  __shared__ float fs[kH];
  if (kc < kN) {
    fs[o] = h2f[((size_t)kc * kB + b) * kH + o];
  } else {
    float v = bspec[o];
#pragma unroll
    for (int s = 0; s < kSpec; ++s) v += spec[b * kSpec + s] * Wspec[s * kH + o];
    fs[o] = v;
  }
  __syncthreads();
  const float* __restrict__ wp = Wp1 + (size_t)kc * 256 * kH + o;
  float a = 0.f;
#pragma unroll 8
  for (int i = 0; i < 256; ++i) a += fs[i] * wp[(size_t)i * kH];
  partial[((size_t)kc * kB + b) * kH + o] = a;
}

__global__ __launch_bounds__(256) void k_head2(
    const float* __restrict__ bp1, const float* __restrict__ Wp2,
    const float* __restrict__ bp2, const float* __restrict__ partial,
    float* __restrict__ out)
{
  const int b = blockIdx.x;
  const int o = threadIdx.x;
  __shared__ float hid[kH];
  float a = bp1[o];
#pragma unroll
  for (int kc = 0; kc < kN + 1; ++kc) a += partial[((size_t)kc * kB + b) * kH + o];
  hid[o] = fmaxf(a, 0.f);
  __syncthreads();
  if (o < kOut) {
    float r = bp2[o];
#pragma unroll 8
    for (int h = 0; h < kH; ++h) r += hid[h] * Wp2[h * kOut + o];
    out[b * kOut + o] = r;
  }
}

extern "C" void kernel_launch(void* const* d_in, const int* in_sizes, int n_in,
                              void* d_out, int out_size, void* d_ws, size_t ws_size,
                              hipStream_t stream) {
  const float* x = (const float*)d_in[0];
  const float* spec = (const float*)d_in[1];
  const float* Wih1 = (const float*)d_in[2];
  const float* Whh1 = (const float*)d_in[3];
  const float* bih1 = (const float*)d_in[4];
  const float* bhh1 = (const float*)d_in[5];
  const float* Wih2 = (const float*)d_in[6];
  const float* Whh2 = (const float*)d_in[7];
  const float* bih2 = (const float*)d_in[8];
  const float* bhh2 = (const float*)d_in[9];
  const float* Wspec = (const float*)d_in[10];
  const float* bspec = (const float*)d_in[11];
  const float* Wp1 = (const float*)d_in[12];
  const float* bp1 = (const float*)d_in[13];
  const float* Wp2 = (const float*)d_in[14];
  const float* bp2 = (const float*)d_in[15];
  float* out = (float*)d_out;

  // ws (~80 MB): [prog 4K][h1r 18.9M][h2r 2.4M][pk1|pk2i|pk2h 56.6M][h2_final][partial]
  // Only prog is memset; tagged rings are self-validating (stale tags never match).
  const size_t WSZ = (size_t)kN * kG * kH;
  u32* prog = (u32*)d_ws;
  u64* h1r = (u64*)((char*)d_ws + 4096);                    // 36*16*4096 u64 = 18.87 MB
  u64* h2r = h1r + (size_t)kN * kD1 * 4096;                 // 36*2*4096 u64 = 2.36 MB
  bf16* pk1 = (bf16*)(h2r + (size_t)kN * 2 * 4096);
  bf16* pk2i = pk1 + WSZ;
  bf16* pk2h = pk2i + WSZ;
  float* h2_final = (float*)(pk2h + WSZ);
  float* partial = h2_final + (size_t)kN * kB * kH;

  hipMemsetAsync(d_ws, 0, 4096, stream); // progress counters only

  const size_t groups = (size_t)kN * 64 * 8 * 64;
  k_convert<<<dim3((unsigned)((groups + 255) / 256)), dim3(256), 0, stream>>>(
      Whh1, Wih2, Whh2, pk1, pk2i, pk2h);
  k_lstm<<<dim3(216), dim3(256), 0, stream>>>(
      x, Wih1, bih1, bhh1, bih2, bhh2, pk1, pk2i, pk2h, h2_final, h1r, h2r, prog);
  k_head1<<<dim3(kN + 1, kB), dim3(256), 0, stream>>>(spec, Wspec, bspec, Wp1, h2_final, partial);
  k_head2<<<dim3(kB), dim3(256), 0, stream>>>(bp1, Wp2, bp2, partial, out);
}

// Round 8
// 964.507 us; speedup vs baseline: 1.9472x; 1.0419x over previous
//
#include <hip/hip_runtime.h>
#include <cstdint>
#include <cstddef>

// LSTMClassifier R14: same-XCD fast lane (XCD-L2 exchange) + tag-validated fallback.
// R13 post-mortem: own-K-first regressed; reverted to R11 base (875us). Eight levers:
// only wait-latency cuts ever helped; cycles/step invariant. Re-derivation at 2.4GHz:
// ~16,400cy/step, ~10,000cy pure wait. Never-attacked mechanism: agent-scope atomics
// bypass the XCD-local L2 (WRITE/FETCH_SIZE confirm all exchange traffic hits TCC) ->
// every exchange pays a loaded LLC RTT. R14:
//  - Stream n's 6 WGs grouped on XCD n%8 (blk%8 round-robin assumption; grid 240).
//  - Producers DUAL-publish: R11 slow path (tagged agent atomics, unchanged) + plain
//    stores into a per-stream fast mirror (plain stores land in XCD L2; L1 is
//    write-through). Same tagged packet bits.
//  - Consumers poll the fast mirror first with inline-asm sc0 loads (L1-bypass,
//    L2-served, ~250cy/iter) under budget=12; tags self-validate. Miss -> fall back
//    to the untouched R11 slow poll (loads pre-issued at prev step's tail). 4
//    consecutive misses -> fast lane self-disables (=R11 + epsilon).
// Correctness is mapping-independent (fallback); numerics bit-identical to R11.

constexpr int kN = 36, kH = 256, kG = 1024, kB = 32, kT = 128, kSpec = 6, kOut = 30;
constexpr int kHP = 264;   // LDS h stride (ushort)
constexpr int kD1 = 16;    // h1 ring depth (steps)

typedef __bf16 bf16;
typedef __bf16 bf16x8 __attribute__((ext_vector_type(8)));
typedef float f32x4 __attribute__((ext_vector_type(4)));
typedef unsigned long long u64;
typedef unsigned int u32;

__device__ __forceinline__ float rcpf(float v) { return __builtin_amdgcn_rcpf(v); }
__device__ __forceinline__ float sigm(float v) { return rcpf(1.f + __expf(-v)); }
__device__ __forceinline__ float tanh_f(float v) {
  return fmaf(-2.f, rcpf(1.f + __expf(2.f * v)), 1.f);
}
__device__ __forceinline__ unsigned short f2bf(float f) {
  bf16 b = (bf16)f;
  return __builtin_bit_cast(unsigned short, b);
}
__device__ __forceinline__ u64 pload(const u64* p) {
  return __hip_atomic_load(p, __ATOMIC_RELAXED, __HIP_MEMORY_SCOPE_AGENT);
}
__device__ __forceinline__ void pstore(u64* p, u64 v) {
  __hip_atomic_store(p, v, __ATOMIC_RELAXED, __HIP_MEMORY_SCOPE_AGENT);
}
__device__ __forceinline__ u32 pload32(const u32* p) {
  return __hip_atomic_load(p, __ATOMIC_RELAXED, __HIP_MEMORY_SCOPE_AGENT);
}
__device__ __forceinline__ void pstore32(u32* p, u32 v) {
  __hip_atomic_store(p, v, __ATOMIC_RELAXED, __HIP_MEMORY_SCOPE_AGENT);
}

// Packet grid per h-matrix: p = m*256 + c, m=0..15 (rows m and m+16), c=0..255.
// payload: lo16 = row m, hi16 = row m+16, tag = high u32.

__device__ __forceinline__ void issue16(const u64* __restrict__ base, int tid, u64* v) {
#pragma unroll
  for (int i = 0; i < 16; ++i) v[i] = pload(base + (size_t)i * 256 + tid);
}
__device__ __forceinline__ void finish16(const u64* __restrict__ base, u32 want,
                                         int tid, u64* v) {
  u32 got = 0;
  for (;;) {
#pragma unroll
    for (int i = 0; i < 16; ++i)
      if (!(got & (1u << i)) && (u32)(v[i] >> 32) == want) got |= 1u << i;
    if (got == 0xFFFFu) return;
#pragma unroll
    for (int i = 0; i < 16; ++i)
      if (!(got & (1u << i))) v[i] = pload(base + (size_t)i * 256 + tid);
  }
}
__device__ __forceinline__ void finish16_stage(const u64* __restrict__ base, u32 want,
                                               int tid, unsigned short (*hs)[kHP],
                                               u64* v) {
  u32 got = 0;
  for (;;) {
#pragma unroll
    for (int i = 0; i < 16; ++i) {
      if (!(got & (1u << i)) && (u32)(v[i] >> 32) == want) {
        got |= 1u << i;
        hs[i][tid] = (unsigned short)v[i];
        hs[i + 16][tid] = (unsigned short)(v[i] >> 16);
      }
    }
    if (got == 0xFFFFu) return;
#pragma unroll
    for (int i = 0; i < 16; ++i)
      if (!(got & (1u << i))) v[i] = pload(base + (size_t)i * 256 + tid);
  }
}
// L1 sibling half: 8 packets/thread over cols [pc0,pc0+128)
__device__ __forceinline__ void issue8h(const u64* __restrict__ base, int tid, int pc0,
                                        u64* v) {
  const int c = pc0 + (tid & 127), m0 = (tid >> 7) * 8;
#pragma unroll
  for (int i = 0; i < 8; ++i) v[i] = pload(base + (size_t)(m0 + i) * 256 + c);
}
__device__ __forceinline__ void finish8_stage(const u64* __restrict__ base, u32 want,
                                              int tid, int pc0,
                                              unsigned short (*hs)[kHP], u64* v) {
  const int c = pc0 + (tid & 127), m0 = (tid >> 7) * 8;
  u32 got = 0;
  for (;;) {
#pragma unroll
    for (int i = 0; i < 8; ++i) {
      if (!(got & (1u << i)) && (u32)(v[i] >> 32) == want) {
        got |= 1u << i;
        hs[m0 + i][c] = (unsigned short)v[i];
        hs[m0 + i + 16][c] = (unsigned short)(v[i] >> 16);
      }
    }
    if (got == 0xFFu) return;
#pragma unroll
    for (int i = 0; i < 8; ++i)
      if (!(got & (1u << i))) v[i] = pload(base + (size_t)(m0 + i) * 256 + c);
  }
}

// ---- fast lane: sc0 (L1-bypass, XCD-L2-served) batched loads via inline asm ----
// 16 packets p = i*256 + tid. 4 base addrs, imm offsets {-4096,-2048,0,2048}.
__device__ __forceinline__ void fast_load16(const u64* fb, int tid, u64* v) {
  const u64* b0 = fb + 2 * 256 + tid;
  const u64* b1 = fb + 6 * 256 + tid;
  const u64* b2 = fb + 10 * 256 + tid;
  const u64* b3 = fb + 14 * 256 + tid;
  asm volatile(
      "global_load_dwordx2 %0, %16, off offset:-4096 sc0\n\t"
      "global_load_dwordx2 %1, %16, off offset:-2048 sc0\n\t"
      "global_load_dwordx2 %2, %16, off sc0\n\t"
      "global_load_dwordx2 %3, %16, off offset:2048 sc0\n\t"
      "global_load_dwordx2 %4, %17, off offset:-4096 sc0\n\t"
      "global_load_dwordx2 %5, %17, off offset:-2048 sc0\n\t"
      "global_load_dwordx2 %6, %17, off sc0\n\t"
      "global_load_dwordx2 %7, %17, off offset:2048 sc0\n\t"
      "global_load_dwordx2 %8, %18, off offset:-4096 sc0\n\t"
      "global_load_dwordx2 %9, %18, off offset:-2048 sc0\n\t"
      "global_load_dwordx2 %10, %18, off sc0\n\t"
      "global_load_dwordx2 %11, %18, off offset:2048 sc0\n\t"
      "global_load_dwordx2 %12, %19, off offset:-4096 sc0\n\t"
      "global_load_dwordx2 %13, %19, off offset:-2048 sc0\n\t"
      "global_load_dwordx2 %14, %19, off sc0\n\t"
      "global_load_dwordx2 %15, %19, off offset:2048 sc0\n\t"
      "s_waitcnt vmcnt(0)"
      : "=v"(v[0]), "=v"(v[1]), "=v"(v[2]), "=v"(v[3]),
        "=v"(v[4]), "=v"(v[5]), "=v"(v[6]), "=v"(v[7]),
        "=v"(v[8]), "=v"(v[9]), "=v"(v[10]), "=v"(v[11]),
        "=v"(v[12]), "=v"(v[13]), "=v"(v[14]), "=v"(v[15])
      : "v"(b0), "v"(b1), "v"(b2), "v"(b3)
      : "memory");
}
__device__ __forceinline__ bool fast_try16(const u64* fb, u32 want, int tid, u64* v,
                                           int budget) {
  for (int it = 0; it < budget; ++it) {
    fast_load16(fb, tid, v);
    bool all = true;
#pragma unroll
    for (int i = 0; i < 16; ++i) all &= ((u32)(v[i] >> 32) == want);
    if (all) return true;
  }
  return false;
}
// 8 packets p = (m0+i)*256 + c (L1 sibling half)
__device__ __forceinline__ void fast_load8(const u64* fb, int tid, int pc0, u64* v) {
  const int c = pc0 + (tid & 127), m0 = (tid >> 7) * 8;
  const u64* b0 = fb + (size_t)(m0 + 2) * 256 + c;
  const u64* b1 = fb + (size_t)(m0 + 6) * 256 + c;
  asm volatile(
      "global_load_dwordx2 %0, %8, off offset:-4096 sc0\n\t"
      "global_load_dwordx2 %1, %8, off offset:-2048 sc0\n\t"
      "global_load_dwordx2 %2, %8, off sc0\n\t"
      "global_load_dwordx2 %3, %8, off offset:2048 sc0\n\t"
      "global_load_dwordx2 %4, %9, off offset:-4096 sc0\n\t"
      "global_load_dwordx2 %5, %9, off offset:-2048 sc0\n\t"
      "global_load_dwordx2 %6, %9, off sc0\n\t"
      "global_load_dwordx2 %7, %9, off offset:2048 sc0\n\t"
      "s_waitcnt vmcnt(0)"
      : "=v"(v[0]), "=v"(v[1]), "=v"(v[2]), "=v"(v[3]),
        "=v"(v[4]), "=v"(v[5]), "=v"(v[6]), "=v"(v[7])
      : "v"(b0), "v"(b1)
      : "memory");
}
__device__ __forceinline__ bool fast_try8(const u64* fb, u32 want, int tid, int pc0,
                                          u64* v, int budget) {
  for (int it = 0; it < budget; ++it) {
    fast_load8(fb, tid, pc0, v);
    bool all = true;
#pragma unroll
    for (int i = 0; i < 8; ++i) all &= ((u32)(v[i] >> 32) == want);
    if (all) return true;
  }
  return false;
}

// ---- convert + permute weights fp32 -> bf16 MFMA B-fragment order ----
__global__ __launch_bounds__(256) void k_convert(
    const float* __restrict__ wa, const float* __restrict__ wb, const float* __restrict__ wc,
    bf16* __restrict__ oa, bf16* __restrict__ ob, bf16* __restrict__ oc)
{
  const size_t total = (size_t)kN * 64 * 8 * 64;
  size_t gid = (size_t)blockIdx.x * 256 + threadIdx.x;
  if (gid >= total) return;
  const int lane = (int)(gid & 63);
  const int ks = (int)((gid >> 6) & 7);
  const int nt = (int)((gid >> 9) & 63);
  const int n = (int)(gid >> 15);
  const int g = nt * 16 + (lane & 15);
  const int k = ks * 32 + (lane >> 4) * 8;
  const size_t so = ((size_t)n * kG + g) * kH + k;

  const float4 a0 = *(const float4*)(wa + so), a1 = *(const float4*)(wa + so + 4);
  const float4 b0 = *(const float4*)(wb + so), b1 = *(const float4*)(wb + so + 4);
  const float4 c0 = *(const float4*)(wc + so), c1 = *(const float4*)(wc + so + 4);
  bf16x8 va, vb, vc;
  va[0]=(bf16)a0.x; va[1]=(bf16)a0.y; va[2]=(bf16)a0.z; va[3]=(bf16)a0.w;
  va[4]=(bf16)a1.x; va[5]=(bf16)a1.y; va[6]=(bf16)a1.z; va[7]=(bf16)a1.w;
  vb[0]=(bf16)b0.x; vb[1]=(bf16)b0.y; vb[2]=(bf16)b0.z; vb[3]=(bf16)b0.w;
  vb[4]=(bf16)b1.x; vb[5]=(bf16)b1.y; vb[6]=(bf16)b1.z; vb[7]=(bf16)b1.w;
  vc[0]=(bf16)c0.x; vc[1]=(bf16)c0.y; vc[2]=(bf16)c0.z; vc[3]=(bf16)c0.w;
  vc[4]=(bf16)c1.x; vc[5]=(bf16)c1.y; vc[6]=(bf16)c1.z; vc[7]=(bf16)c1.w;
  ((bf16x8*)oa)[gid] = va;
  ((bf16x8*)ob)[gid] = vb;
  ((bf16x8*)oc)[gid] = vc;
}

// MFMA over 4 K-slices [KS0, KS0+4) of hs1 against W (L1). KS0 must be a literal.
#define L1_MFMA_HALF(KS0)                                                            \
  _Pragma("unroll")                                                                  \
  for (int kk = 0; kk < 4; ++kk) {                                                   \
    const int ks = (KS0) + kk;                                                       \
    bf16x8 A0 = *(const bf16x8*)&hs1[l15][ks * 32 + l4 * 8];                         \
    bf16x8 A1 = *(const bf16x8*)&hs1[16 + l15][ks * 32 + l4 * 8];                    \
    _Pragma("unroll")                                                                \
    for (int jj = 0; jj < 2; ++jj)                                                   \
      _Pragma("unroll")                                                              \
      for (int gt = 0; gt < 4; ++gt) {                                               \
        acc[0][jj][gt] = __builtin_amdgcn_mfma_f32_16x16x32_bf16(                    \
            A0, W[jj][gt][ks], acc[0][jj][gt], 0, 0, 0);                             \
        acc[1][jj][gt] = __builtin_amdgcn_mfma_f32_16x16x32_bf16(                    \
            A1, W[jj][gt][ks], acc[1][jj][gt], 0, 0, 0);                             \
      }                                                                              \
  }

// ---- two concurrent recurrent chains ----
// Grid 240: blk -> xcd = blk%8, s = blk/8, k = s/6, w = s%6, n = k*8 + xcd.
// All 6 WGs of stream n share xcd (if blk%8->XCD round-robin holds; else fallback).
__global__ __launch_bounds__(256) __attribute__((amdgpu_waves_per_eu(1, 1)))
void k_lstm(
    const float* __restrict__ x, const float* __restrict__ Wih1,
    const float* __restrict__ bih1, const float* __restrict__ bhh1,
    const float* __restrict__ bih2, const float* __restrict__ bhh2,
    const bf16* __restrict__ pk1, const bf16* __restrict__ pk2i,
    const bf16* __restrict__ pk2h, float* __restrict__ h2_final,
    u64* __restrict__ h1r, u64* __restrict__ h2r,
    u64* __restrict__ fh1, u64* __restrict__ fh2, u32* __restrict__ prog)
{
  const int blk = blockIdx.x;
  const int xcd = blk & 7, sl = blk >> 3;
  const int kk_ = sl / 6, w = sl - kk_ * 6;
  const int n = kk_ * 8 + xcd;
  if (n >= kN) return;
  const int tid = threadIdx.x, wv = tid >> 6, lane = tid & 63;
  const int l15 = lane & 15, l4 = lane >> 4;

  __shared__ alignas(16) unsigned short hs1[kB][kHP];

  if (w < 2) {
    // ================= L1: h1 chain; WG j owns h1-cols [j*128,(j+1)*128) =========
    const int j = w;
    __shared__ float xsh[kT][kB];
    for (int i = tid; i < kB * kT; i += 256) {
      int b = i >> 7, t = i & 127;
      xsh[t][b] = x[((size_t)b * kT + t) * kN + n];
    }
    bf16x8 W[2][4][8]; // 256 VGPRs
    {
      const bf16x8* base = (const bf16x8*)pk1 + (size_t)n * 32768;
#pragma unroll
      for (int jj = 0; jj < 2; ++jj)
#pragma unroll
        for (int gt = 0; gt < 4; ++gt)
#pragma unroll
          for (int ks = 0; ks < 8; ++ks)
            W[jj][gt][ks] = base[(size_t)(gt * 16 + j * 8 + wv * 2 + jj) * 512 + ks * 64 + lane];
    }
    float wih[2][4], bg[2][4];
#pragma unroll
    for (int jj = 0; jj < 2; ++jj)
#pragma unroll
      for (int gt = 0; gt < 4; ++gt) {
        int g = gt * 256 + j * 128 + wv * 32 + jj * 16 + l15;
        wih[jj][gt] = Wih1[n * kG + g];
        bg[jj][gt] = bih1[n * kG + g] + bhh1[n * kG + g];
      }
    float cst[2][2][4];
#pragma unroll
    for (int a = 0; a < 2; ++a)
#pragma unroll
      for (int b = 0; b < 2; ++b)
#pragma unroll
        for (int r = 0; r < 4; ++r) cst[a][b][r] = 0.f;

    u64* ringn = h1r + (size_t)n * kD1 * 4096;
    u64* fh1n = fh1 + (size_t)n * 2 * 4096;
    u32* pg = prog + n * 4;
    const int pc0 = (1 - j) * 128, myb = j * 128 + wv * 32;
    u64 pv[8], vf[8];
    int fen = 1, fmiss = 0;
    __syncthreads();

#pragma unroll 1
    for (int t = 0; t < kT; ++t) {
      if ((t & 7) == 0 && t) { // ring back-pressure vs slowest L2 quarter
        if (tid == 0) {
          for (;;) {
            u32 m0 = pload32(&pg[0]), m1 = pload32(&pg[1]);
            u32 m2 = pload32(&pg[2]), m3 = pload32(&pg[3]);
            u32 mn = m0 < m1 ? m0 : m1;
            mn = mn < m2 ? mn : m2;
            mn = mn < m3 ? mn : m3;
            if ((int)mn + 8 >= t) break;
          }
        }
        __syncthreads();
      }
      f32x4 acc[2][2][4];
#pragma unroll
      for (int mt = 0; mt < 2; ++mt)
#pragma unroll
        for (int jj = 0; jj < 2; ++jj)
#pragma unroll
          for (int gt = 0; gt < 4; ++gt)
#pragma unroll
            for (int r = 0; r < 4; ++r)
              acc[mt][jj][gt][r] = xsh[t][mt * 16 + l4 * 4 + r] * wih[jj][gt] + bg[jj][gt];
      if (t > 0) {
        const u64* ps = ringn + (size_t)((t - 1) % kD1) * 4096;
        // own K-half first (LDS-resident); sibling fast/slow detect after.
        if (j == 0) { L1_MFMA_HALF(0) } else { L1_MFMA_HALF(4) }
        bool fok = false;
        if (fen) fok = fast_try8(fh1n + (size_t)((t - 1) & 1) * 4096, (u32)t, tid, pc0, vf, 12);
        if (fok) {
          const int c = pc0 + (tid & 127), m0 = (tid >> 7) * 8;
          fmiss = 0;
#pragma unroll
          for (int i = 0; i < 8; ++i) {
            hs1[m0 + i][c] = (unsigned short)vf[i];
            hs1[m0 + i + 16][c] = (unsigned short)(vf[i] >> 16);
          }
        } else {
          if (fen && ++fmiss >= 4) fen = 0;
          finish8_stage(ps, (u32)t, tid, pc0, hs1, pv);
        }
        __syncthreads();
        if (j == 0) { L1_MFMA_HALF(4) } else { L1_MFMA_HALF(0) }
      }
      // cell + dual publish (slow tagged atomics + fast plain mirror)
      u64* pub = ringn + (size_t)(t % kD1) * 4096;
      u64* fpub = fh1n + (size_t)(t & 1) * 4096;
      const u64 tagw = ((u64)(u32)(t + 1)) << 32;
      float hv[2][2][4];
#pragma unroll
      for (int jj = 0; jj < 2; ++jj) {
#pragma unroll
        for (int mt = 0; mt < 2; ++mt)
#pragma unroll
          for (int r = 0; r < 4; ++r) {
            float cc = sigm(acc[mt][jj][1][r]) * cst[mt][jj][r]
                     + sigm(acc[mt][jj][0][r]) * tanh_f(acc[mt][jj][2][r]);
            cst[mt][jj][r] = cc;
            hv[mt][jj][r] = sigm(acc[mt][jj][3][r]) * tanh_f(cc);
          }
#pragma unroll
        for (int r = 0; r < 4; ++r) {
          int c = myb + jj * 16 + l15, m = l4 * 4 + r;
          u64 pkt = tagw | ((u64)f2bf(hv[1][jj][r]) << 16) | f2bf(hv[0][jj][r]);
          fpub[(size_t)m * 256 + c] = pkt;   // fast mirror (XCD L2)
          pstore(&pub[(size_t)m * 256 + c], pkt);
        }
      }
      // own half straight into LDS for next step
#pragma unroll
      for (int mt = 0; mt < 2; ++mt)
#pragma unroll
        for (int jj = 0; jj < 2; ++jj)
#pragma unroll
          for (int r = 0; r < 4; ++r)
            hs1[mt * 16 + l4 * 4 + r][myb + jj * 16 + l15] = f2bf(hv[mt][jj][r]);
      if (t + 1 < kT) issue8h(pub, tid, pc0, pv); // slow prefetch (fallback fuel)
      __syncthreads();
    }
  } else {
    // ====== L2: h2 chain; WG q owns h2-cols [q*64,(q+1)*64); u in-register =======
    const int q = w - 2;
    __shared__ alignas(16) unsigned short hs2[kB][kHP];

    bf16x8 Wi[4][8], Wh[4][8]; // 128 + 128 VGPRs
    {
      const bf16x8* bi = (const bf16x8*)pk2i + (size_t)n * 32768;
      const bf16x8* bh = (const bf16x8*)pk2h + (size_t)n * 32768;
#pragma unroll
      for (int gt = 0; gt < 4; ++gt)
#pragma unroll
        for (int ks = 0; ks < 8; ++ks) {
          size_t o = (size_t)(gt * 16 + q * 4 + wv) * 512 + ks * 64 + lane;
          Wi[gt][ks] = bi[o];
          Wh[gt][ks] = bh[o];
        }
    }
    const int col = q * 64 + wv * 16 + l15;
    float bg[4];
#pragma unroll
    for (int gt = 0; gt < 4; ++gt) {
      int g = gt * 256 + col;
      bg[gt] = bih2[n * kG + g] + bhh2[n * kG + g];
    }
    float cst[2][4];
#pragma unroll
    for (int mt = 0; mt < 2; ++mt)
#pragma unroll
      for (int r = 0; r < 4; ++r) cst[mt][r] = 0.f;

    u64* ringn = h1r + (size_t)n * kD1 * 4096;
    u64* h2n = h2r + (size_t)n * 2 * 4096;
    u64* fh2n = fh2 + (size_t)n * 2 * 4096;
    u32* pg = prog + n * 4 + q;
    int fen = 1, fmiss = 0;
    __syncthreads();

    // prologue: h1(0), ring slot 0, tag 1
    u64 v1[16], v2[16], vf[16];
    issue16(ringn, tid, v1);
    finish16(ringn, 1u, tid, v1);

#pragma unroll 1
    for (int t = 0; t < kT; ++t) {
      // (A) stage prefetched h1(t) into hs1
#pragma unroll
      for (int i = 0; i < 16; ++i) {
        hs1[i][tid] = (unsigned short)v1[i];
        hs1[i + 16][tid] = (unsigned short)(v1[i] >> 16);
      }
      __syncthreads();
      if (tid == 0) pstore32(pg, (u32)(t + 1)); // h1(t) consumed; ring slot reusable
      // (B) fire h1(t+1) prefetch; h2(t-1) slow loads were issued at END of t-1
      const u64* pn = ringn + (size_t)((t + 1) % kD1) * 4096;
      if (t + 1 < kT) issue16(pn, tid, v1);
      // (C) u = Wih2 * h1(t) + bg2 (h2 propagate hidden under A+B+C)
      f32x4 acc[2][4];
#pragma unroll
      for (int mt = 0; mt < 2; ++mt)
#pragma unroll
        for (int gt = 0; gt < 4; ++gt)
#pragma unroll
          for (int r = 0; r < 4; ++r) acc[mt][gt][r] = bg[gt];
#pragma unroll
      for (int ks = 0; ks < 8; ++ks) {
        bf16x8 A0 = *(const bf16x8*)&hs1[l15][ks * 32 + l4 * 8];
        bf16x8 A1 = *(const bf16x8*)&hs1[16 + l15][ks * 32 + l4 * 8];
#pragma unroll
        for (int gt = 0; gt < 4; ++gt) {
          acc[0][gt] = __builtin_amdgcn_mfma_f32_16x16x32_bf16(A0, Wi[gt][ks], acc[0][gt], 0, 0, 0);
          acc[1][gt] = __builtin_amdgcn_mfma_f32_16x16x32_bf16(A1, Wi[gt][ks], acc[1][gt], 0, 0, 0);
        }
      }
      // (D) h2(t-1): fast-lane try, fallback = R11 slow validate+stage
      if (t > 0) {
        bool fok = false;
        if (fen) fok = fast_try16(fh2n + (size_t)((t - 1) & 1) * 4096, (u32)t, tid, vf, 12);
        if (fok) {
          fmiss = 0;
#pragma unroll
          for (int i = 0; i < 16; ++i) {
            hs2[i][tid] = (unsigned short)vf[i];
            hs2[i + 16][tid] = (unsigned short)(vf[i] >> 16);
          }
        } else {
          if (fen && ++fmiss >= 4) fen = 0;
          finish16_stage(h2n + (size_t)((t - 1) & 1) * 4096, (u32)t, tid, hs2, v2);
        }
        __syncthreads();
#pragma unroll
        for (int ks = 0; ks < 8; ++ks) {
          bf16x8 A0 = *(const bf16x8*)&hs2[l15][ks * 32 + l4 * 8];
          bf16x8 A1 = *(const bf16x8*)&hs2[16 + l15][ks * 32 + l4 * 8];
#pragma unroll
          for (int gt = 0; gt < 4; ++gt) {
            acc[0][gt] = __builtin_amdgcn_mfma_f32_16x16x32_bf16(A0, Wh[gt][ks], acc[0][gt], 0, 0, 0);
            acc[1][gt] = __builtin_amdgcn_mfma_f32_16x16x32_bf16(A1, Wh[gt][ks], acc[1][gt], 0, 0, 0);
          }
        }
      }
      // (E) cell + dual publish interleaved per r
      u64* pub = h2n + (size_t)(t & 1) * 4096;
      u64* fpub = fh2n + (size_t)(t & 1) * 4096;
      const u64 tagw = ((u64)(u32)(t + 1)) << 32;
      float hv[2][4];
#pragma unroll
      for (int r = 0; r < 4; ++r) {
#pragma unroll
        for (int mt = 0; mt < 2; ++mt) {
          float cc = sigm(acc[mt][1][r]) * cst[mt][r]
                   + sigm(acc[mt][0][r]) * tanh_f(acc[mt][2][r]);
          cst[mt][r] = cc;
          hv[mt][r] = sigm(acc[mt][3][r]) * tanh_f(cc);
        }
        u64 pkt = tagw | ((u64)f2bf(hv[1][r]) << 16) | f2bf(hv[0][r]);
        fpub[(size_t)(l4 * 4 + r) * 256 + col] = pkt;  // fast mirror (XCD L2)
        pstore(&pub[(size_t)(l4 * 4 + r) * 256 + col], pkt);
      }
      if (t == kT - 1) {
#pragma unroll
        for (int mt = 0; mt < 2; ++mt)
#pragma unroll
          for (int r = 0; r < 4; ++r)
            h2_final[((size_t)n * kB + (mt * 16 + l4 * 4 + r)) * kH + col] = hv[mt][r];
      }
      // (E2) early-issue next h2 slow loads (fallback fuel; coalesced unchanged)
      if (t + 1 < kT) issue16(pub, tid, v2);
      // (F) validate h1(t+1) prefetch (usually already arrived)
      if (t + 1 < kT) finish16(pn, (u32)(t + 2), tid, v1);
      __syncthreads(); // all MFMA reads done before staging at next (A)
    }
  }
}

// ---- head ----
__global__ __launch_bounds__(256) void k_head1(
    const float* __restrict__ spec, const float* __restrict__ Wspec,
    const float* __restrict__ bspec, const float* __restrict__ Wp1,
    const float* __restrict__ h2f, float* __restrict__ partial)
{
  const int kc = blockIdx.x;
  const int b = blockIdx.y;
  const int o = threadIdx.x;
  __shared__ float fs[kH];
  if (kc < kN) {
    fs[o] = h2f[((size_t)kc * kB + b) * kH + o];
  } else {
    float v = bspec[o];
#pragma unroll
    for (int s = 0; s < kSpec; ++s) v += spec[b * kSpec + s] * Wspec[s * kH + o];
    fs[o] = v;
  }
  __syncthreads();
  const float* __restrict__ wp = Wp1 + (size_t)kc * 256 * kH + o;
  float a = 0.f;
#pragma unroll 8
  for (int i = 0; i < 256; ++i) a += fs[i] * wp[(size_t)i * kH];
  partial[((size_t)kc * kB + b) * kH + o] = a;
}

__global__ __launch_bounds__(256) void k_head2(
    const float* __restrict__ bp1, const float* __restrict__ Wp2,
    const float* __restrict__ bp2, const float* __restrict__ partial,
    float* __restrict__ out)
{
  const int b = blockIdx.x;
  const int o = threadIdx.x;
  __shared__ float hid[kH];
  float a = bp1[o];
#pragma unroll
  for (int kc = 0; kc < kN + 1; ++kc) a += partial[((size_t)kc * kB + b) * kH + o];
  hid[o] = fmaxf(a, 0.f);
  __syncthreads();
  if (o < kOut) {
    float r = bp2[o];
#pragma unroll 8
    for (int h = 0; h < kH; ++h) r += hid[h] * Wp2[h * kOut + o];
    out[b * kOut + o] = r;
  }
}

extern "C" void kernel_launch(void* const* d_in, const int* in_sizes, int n_in,
                              void* d_out, int out_size, void* d_ws, size_t ws_size,
                              hipStream_t stream) {
  const float* x = (const float*)d_in[0];
  const float* spec = (const float*)d_in[1];
  const float* Wih1 = (const float*)d_in[2];
  const float* Whh1 = (const float*)d_in[3];
  const float* bih1 = (const float*)d_in[4];
  const float* bhh1 = (const float*)d_in[5];
  const float* Wih2 = (const float*)d_in[6];
  const float* Whh2 = (const float*)d_in[7];
  const float* bih2 = (const float*)d_in[8];
  const float* bhh2 = (const float*)d_in[9];
  const float* Wspec = (const float*)d_in[10];
  const float* bspec = (const float*)d_in[11];
  const float* Wp1 = (const float*)d_in[12];
  const float* bp1 = (const float*)d_in[13];
  const float* Wp2 = (const float*)d_in[14];
  const float* bp2 = (const float*)d_in[15];
  float* out = (float*)d_out;

  // ws (~85 MB): [prog 4K][h1r 18.9M][h2r 2.4M][fh1 2.4M][fh2 2.4M]
  //              [pk1|pk2i|pk2h 56.6M][h2_final][partial]
  // Only prog is memset. Slow rings self-validate via tags; fast mirrors also
  // tag-validated (stale/garbage -> fallback), so no zeroing needed.
  const size_t WSZ = (size_t)kN * kG * kH;
  u32* prog = (u32*)d_ws;
  u64* h1r = (u64*)((char*)d_ws + 4096);                    // 36*16*4096 u64
  u64* h2r = h1r + (size_t)kN * kD1 * 4096;                 // 36*2*4096 u64
  u64* fh1 = h2r + (size_t)kN * 2 * 4096;                   // 36*2*4096 u64
  u64* fh2 = fh1 + (size_t)kN * 2 * 4096;                   // 36*2*4096 u64
  bf16* pk1 = (bf16*)(fh2 + (size_t)kN * 2 * 4096);
  bf16* pk2i = pk1 + WSZ;
  bf16* pk2h = pk2i + WSZ;
  float* h2_final = (float*)(pk2h + WSZ);
  float* partial = h2_final + (size_t)kN * kB * kH;

  hipMemsetAsync(d_ws, 0, 4096, stream); // progress counters only

  const size_t groups = (size_t)kN * 64 * 8 * 64;
  k_convert<<<dim3((unsigned)((groups + 255) / 256)), dim3(256), 0, stream>>>(
      Whh1, Wih2, Whh2, pk1, pk2i, pk2h);
  k_lstm<<<dim3(240), dim3(256), 0, stream>>>(
      x, Wih1, bih1, bhh1, bih2, bhh2, pk1, pk2i, pk2h, h2_final,
      h1r, h2r, fh1, fh2, prog);
  k_head1<<<dim3(kN + 1, kB), dim3(256), 0, stream>>>(spec, Wspec, bspec, Wp1, h2_final, partial);
  k_head2<<<dim3(kB), dim3(256), 0, stream>>>(bp1, Wp2, bp2, partial, out);
}

// Round 9
// 897.905 us; speedup vs baseline: 2.0917x; 1.0742x over previous
//
#include <hip/hip_runtime.h>
#include <cstdint>
#include <cstddef>

// LSTMClassifier R15: exact R11 real path + 40 "heater" WGs to defeat DVFS downclock.
// R14 post-mortem: fast XCD-L2 lane WORKED (FETCH 715->220MB) yet dur unchanged ->
// memory-path latency is NOT the critical path. MfmaUtil*dur conserved across 9
// variants => clock constant & cycles invariant. At a hypothesized ~500MHz the
// ~3,400cy/step budget MATCHES the unavoidable serial structure (stage + 640cy MFMA +
// detect + 640cy MFMA + cell + barriers) -> cycles are near floor; the remaining 2-4x
// is CLOCK. Kernel profile (10% occupancy, 90% CUs idle, spin-waits) = max downclock
// signal. R15: grid 216->256; blocks 216..255 are heaters: register-only dependent
// MFMA chains + a completion-flag poll. Real WGs use the full CU VGPR file, so
// heaters can only occupy the 40 idle CUs (cannot co-schedule with real waves).
// Heaters exit when all 144 L2 WGs bump ndone (tail <= ~2us). Real path bit-identical
// to R11 (875us best).

constexpr int kN = 36, kH = 256, kG = 1024, kB = 32, kT = 128, kSpec = 6, kOut = 30;
constexpr int kHP = 264;   // LDS h stride (ushort)
constexpr int kD1 = 16;    // h1 ring depth (steps)

typedef __bf16 bf16;
typedef __bf16 bf16x8 __attribute__((ext_vector_type(8)));
typedef float f32x4 __attribute__((ext_vector_type(4)));
typedef unsigned long long u64;
typedef unsigned int u32;

__device__ __forceinline__ float rcpf(float v) { return __builtin_amdgcn_rcpf(v); }
__device__ __forceinline__ float sigm(float v) { return rcpf(1.f + __expf(-v)); }
__device__ __forceinline__ float tanh_f(float v) {
  return fmaf(-2.f, rcpf(1.f + __expf(2.f * v)), 1.f);
}
__device__ __forceinline__ unsigned short f2bf(float f) {
  bf16 b = (bf16)f;
  return __builtin_bit_cast(unsigned short, b);
}
__device__ __forceinline__ u64 pload(const u64* p) {
  return __hip_atomic_load(p, __ATOMIC_RELAXED, __HIP_MEMORY_SCOPE_AGENT);
}
__device__ __forceinline__ void pstore(u64* p, u64 v) {
  __hip_atomic_store(p, v, __ATOMIC_RELAXED, __HIP_MEMORY_SCOPE_AGENT);
}
__device__ __forceinline__ u32 pload32(const u32* p) {
  return __hip_atomic_load(p, __ATOMIC_RELAXED, __HIP_MEMORY_SCOPE_AGENT);
}
__device__ __forceinline__ void pstore32(u32* p, u32 v) {
  __hip_atomic_store(p, v, __ATOMIC_RELAXED, __HIP_MEMORY_SCOPE_AGENT);
}

// Packet grid per h-matrix: p = m*256 + c, m=0..15 (rows m and m+16), c=0..255.
// payload: lo16 = row m, hi16 = row m+16, tag = high u32.

__device__ __forceinline__ void issue16(const u64* __restrict__ base, int tid, u64* v) {
#pragma unroll
  for (int i = 0; i < 16; ++i) v[i] = pload(base + (size_t)i * 256 + tid);
}
__device__ __forceinline__ void finish16(const u64* __restrict__ base, u32 want,
                                         int tid, u64* v) {
  u32 got = 0;
  for (;;) {
#pragma unroll
    for (int i = 0; i < 16; ++i)
      if (!(got & (1u << i)) && (u32)(v[i] >> 32) == want) got |= 1u << i;
    if (got == 0xFFFFu) return;
#pragma unroll
    for (int i = 0; i < 16; ++i)
      if (!(got & (1u << i))) v[i] = pload(base + (size_t)i * 256 + tid);
  }
}
__device__ __forceinline__ void finish16_stage(const u64* __restrict__ base, u32 want,
                                               int tid, unsigned short (*hs)[kHP],
                                               u64* v) {
  u32 got = 0;
  for (;;) {
#pragma unroll
    for (int i = 0; i < 16; ++i) {
      if (!(got & (1u << i)) && (u32)(v[i] >> 32) == want) {
        got |= 1u << i;
        hs[i][tid] = (unsigned short)v[i];
        hs[i + 16][tid] = (unsigned short)(v[i] >> 16);
      }
    }
    if (got == 0xFFFFu) return;
#pragma unroll
    for (int i = 0; i < 16; ++i)
      if (!(got & (1u << i))) v[i] = pload(base + (size_t)i * 256 + tid);
  }
}
// L1 sibling half: 8 packets/thread over cols [pc0,pc0+128)
__device__ __forceinline__ void issue8h(const u64* __restrict__ base, int tid, int pc0,
                                        u64* v) {
  const int c = pc0 + (tid & 127), m0 = (tid >> 7) * 8;
#pragma unroll
  for (int i = 0; i < 8; ++i) v[i] = pload(base + (size_t)(m0 + i) * 256 + c);
}
__device__ __forceinline__ void finish8_stage(const u64* __restrict__ base, u32 want,
                                              int tid, int pc0,
                                              unsigned short (*hs)[kHP], u64* v) {
  const int c = pc0 + (tid & 127), m0 = (tid >> 7) * 8;
  u32 got = 0;
  for (;;) {
#pragma unroll
    for (int i = 0; i < 8; ++i) {
      if (!(got & (1u << i)) && (u32)(v[i] >> 32) == want) {
        got |= 1u << i;
        hs[m0 + i][c] = (unsigned short)v[i];
        hs[m0 + i + 16][c] = (unsigned short)(v[i] >> 16);
      }
    }
    if (got == 0xFFu) return;
#pragma unroll
    for (int i = 0; i < 8; ++i)
      if (!(got & (1u << i))) v[i] = pload(base + (size_t)(m0 + i) * 256 + c);
  }
}

// ---- convert + permute weights fp32 -> bf16 MFMA B-fragment order ----
__global__ __launch_bounds__(256) void k_convert(
    const float* __restrict__ wa, const float* __restrict__ wb, const float* __restrict__ wc,
    bf16* __restrict__ oa, bf16* __restrict__ ob, bf16* __restrict__ oc)
{
  const size_t total = (size_t)kN * 64 * 8 * 64;
  size_t gid = (size_t)blockIdx.x * 256 + threadIdx.x;
  if (gid >= total) return;
  const int lane = (int)(gid & 63);
  const int ks = (int)((gid >> 6) & 7);
  const int nt = (int)((gid >> 9) & 63);
  const int n = (int)(gid >> 15);
  const int g = nt * 16 + (lane & 15);
  const int k = ks * 32 + (lane >> 4) * 8;
  const size_t so = ((size_t)n * kG + g) * kH + k;

  const float4 a0 = *(const float4*)(wa + so), a1 = *(const float4*)(wa + so + 4);
  const float4 b0 = *(const float4*)(wb + so), b1 = *(const float4*)(wb + so + 4);
  const float4 c0 = *(const float4*)(wc + so), c1 = *(const float4*)(wc + so + 4);
  bf16x8 va, vb, vc;
  va[0]=(bf16)a0.x; va[1]=(bf16)a0.y; va[2]=(bf16)a0.z; va[3]=(bf16)a0.w;
  va[4]=(bf16)a1.x; va[5]=(bf16)a1.y; va[6]=(bf16)a1.z; va[7]=(bf16)a1.w;
  vb[0]=(bf16)b0.x; vb[1]=(bf16)b0.y; vb[2]=(bf16)b0.z; vb[3]=(bf16)b0.w;
  vb[4]=(bf16)b1.x; vb[5]=(bf16)b1.y; vb[6]=(bf16)b1.z; vb[7]=(bf16)b1.w;
  vc[0]=(bf16)c0.x; vc[1]=(bf16)c0.y; vc[2]=(bf16)c0.z; vc[3]=(bf16)c0.w;
  vc[4]=(bf16)c1.x; vc[5]=(bf16)c1.y; vc[6]=(bf16)c1.z; vc[7]=(bf16)c1.w;
  ((bf16x8*)oa)[gid] = va;
  ((bf16x8*)ob)[gid] = vb;
  ((bf16x8*)oc)[gid] = vc;
}

// MFMA over 4 K-slices [KS0, KS0+4) of hs1 against W (L1). KS0 must be a literal.
#define L1_MFMA_HALF(KS0)                                                            \
  _Pragma("unroll")                                                                  \
  for (int kk = 0; kk < 4; ++kk) {                                                   \
    const int ks = (KS0) + kk;                                                       \
    bf16x8 A0 = *(const bf16x8*)&hs1[l15][ks * 32 + l4 * 8];                         \
    bf16x8 A1 = *(const bf16x8*)&hs1[16 + l15][ks * 32 + l4 * 8];                    \
    _Pragma("unroll")                                                                \
    for (int jj = 0; jj < 2; ++jj)                                                   \
      _Pragma("unroll")                                                              \
      for (int gt = 0; gt < 4; ++gt) {                                               \
        acc[0][jj][gt] = __builtin_amdgcn_mfma_f32_16x16x32_bf16(                    \
            A0, W[jj][gt][ks], acc[0][jj][gt], 0, 0, 0);                             \
        acc[1][jj][gt] = __builtin_amdgcn_mfma_f32_16x16x32_bf16(                    \
            A1, W[jj][gt][ks], acc[1][jj][gt], 0, 0, 0);                             \
      }                                                                              \
  }

// ---- two concurrent recurrent chains + heaters ----
// blk<72: L1. 72<=blk<216: L2. 216<=blk<256: heater (real WGs use the full CU VGPR
// file, so heaters can only occupy otherwise-idle CUs).
__global__ __launch_bounds__(256) __attribute__((amdgpu_waves_per_eu(1, 1)))
void k_lstm(
    const float* __restrict__ x, const float* __restrict__ Wih1,
    const float* __restrict__ bih1, const float* __restrict__ bhh1,
    const float* __restrict__ bih2, const float* __restrict__ bhh2,
    const bf16* __restrict__ pk1, const bf16* __restrict__ pk2i,
    const bf16* __restrict__ pk2h, float* __restrict__ h2_final,
    u64* __restrict__ h1r, u64* __restrict__ h2r, u32* __restrict__ prog)
{
  const int blk = blockIdx.x;
  const int tid = threadIdx.x, wv = tid >> 6, lane = tid & 63;
  const int l15 = lane & 15, l4 = lane >> 4;
  u32* ndone = prog + 512; // inside zeroed 4KB prog page

  __shared__ alignas(16) unsigned short hs1[kB][kHP];

  if (blk < 72) {
    // ================= L1: h1 chain; WG j owns h1-cols [j*128,(j+1)*128) =========
    const int n = blk >> 1, j = blk & 1;
    __shared__ float xsh[kT][kB];
    for (int i = tid; i < kB * kT; i += 256) {
      int b = i >> 7, t = i & 127;
      xsh[t][b] = x[((size_t)b * kT + t) * kN + n];
    }
    bf16x8 W[2][4][8]; // 256 VGPRs
    {
      const bf16x8* base = (const bf16x8*)pk1 + (size_t)n * 32768;
#pragma unroll
      for (int jj = 0; jj < 2; ++jj)
#pragma unroll
        for (int gt = 0; gt < 4; ++gt)
#pragma unroll
          for (int ks = 0; ks < 8; ++ks)
            W[jj][gt][ks] = base[(size_t)(gt * 16 + j * 8 + wv * 2 + jj) * 512 + ks * 64 + lane];
    }
    float wih[2][4], bg[2][4];
#pragma unroll
    for (int jj = 0; jj < 2; ++jj)
#pragma unroll
      for (int gt = 0; gt < 4; ++gt) {
        int g = gt * 256 + j * 128 + wv * 32 + jj * 16 + l15;
        wih[jj][gt] = Wih1[n * kG + g];
        bg[jj][gt] = bih1[n * kG + g] + bhh1[n * kG + g];
      }
    float cst[2][2][4];
#pragma unroll
    for (int a = 0; a < 2; ++a)
#pragma unroll
      for (int b = 0; b < 2; ++b)
#pragma unroll
        for (int r = 0; r < 4; ++r) cst[a][b][r] = 0.f;

    u64* ringn = h1r + (size_t)n * kD1 * 4096;
    u32* pg = prog + n * 4;
    const int pc0 = (1 - j) * 128, myb = j * 128 + wv * 32;
    u64 pv[8]; // sibling prefetch, issued at end of step t for use at t+1
    __syncthreads();

#pragma unroll 1
    for (int t = 0; t < kT; ++t) {
      if ((t & 7) == 0 && t) { // ring back-pressure vs slowest L2 quarter
        if (tid == 0) {
          for (;;) {
            u32 m0 = pload32(&pg[0]), m1 = pload32(&pg[1]);
            u32 m2 = pload32(&pg[2]), m3 = pload32(&pg[3]);
            u32 mn = m0 < m1 ? m0 : m1;
            mn = mn < m2 ? mn : m2;
            mn = mn < m3 ? mn : m3;
            if ((int)mn + 8 >= t) break;
          }
        }
        __syncthreads();
      }
      f32x4 acc[2][2][4];
#pragma unroll
      for (int mt = 0; mt < 2; ++mt)
#pragma unroll
        for (int jj = 0; jj < 2; ++jj)
#pragma unroll
          for (int gt = 0; gt < 4; ++gt)
#pragma unroll
            for (int r = 0; r < 4; ++r)
              acc[mt][jj][gt][r] = xsh[t][mt * 16 + l4 * 4 + r] * wih[jj][gt] + bg[jj][gt];
      if (t > 0) {
        const u64* ps = ringn + (size_t)((t - 1) % kD1) * 4096;
        // own K-half first (LDS-resident since end-of-step t-1 barrier); sibling
        // loads were issued at END of step t-1 -> propagate overlapped cell+publish.
        if (j == 0) { L1_MFMA_HALF(0) } else { L1_MFMA_HALF(4) }
        finish8_stage(ps, (u32)t, tid, pc0, hs1, pv);
        __syncthreads();                    // sibling staged, visible to all waves
        if (j == 0) { L1_MFMA_HALF(4) } else { L1_MFMA_HALF(0) }
      }
      // cell + publish interleaved by jj: packets go out as soon as ready
      u64* pub = ringn + (size_t)(t % kD1) * 4096;
      const u64 tagw = ((u64)(u32)(t + 1)) << 32;
      float hv[2][2][4];
#pragma unroll
      for (int jj = 0; jj < 2; ++jj) {
#pragma unroll
        for (int mt = 0; mt < 2; ++mt)
#pragma unroll
          for (int r = 0; r < 4; ++r) {
            float cc = sigm(acc[mt][jj][1][r]) * cst[mt][jj][r]
                     + sigm(acc[mt][jj][0][r]) * tanh_f(acc[mt][jj][2][r]);
            cst[mt][jj][r] = cc;
            hv[mt][jj][r] = sigm(acc[mt][jj][3][r]) * tanh_f(cc);
          }
#pragma unroll
        for (int r = 0; r < 4; ++r) {
          int c = myb + jj * 16 + l15, m = l4 * 4 + r;
          pstore(&pub[(size_t)m * 256 + c],
                 tagw | ((u64)f2bf(hv[1][jj][r]) << 16) | f2bf(hv[0][jj][r]));
        }
      }
      // own half straight into LDS for next step
#pragma unroll
      for (int mt = 0; mt < 2; ++mt)
#pragma unroll
        for (int jj = 0; jj < 2; ++jj)
#pragma unroll
          for (int r = 0; r < 4; ++r)
            hs1[mt * 16 + l4 * 4 + r][myb + jj * 16 + l15] = f2bf(hv[mt][jj][r]);
      // EARLY ISSUE: sibling writes h1(t) into this same slot; fire loads now so
      // propagation + first sample overlap the rest of this step + barrier.
      if (t + 1 < kT) issue8h(pub, tid, pc0, pv);
      __syncthreads(); // own-half visible for next step's pre-barrier own-K MFMA
    }
  } else if (blk < 216) {
    // ====== L2: h2 chain; WG q owns h2-cols [q*64,(q+1)*64); u in-register =======
    const int bb = blk - 72, n = bb >> 2, q = bb & 3;
    __shared__ alignas(16) unsigned short hs2[kB][kHP];

    bf16x8 Wi[4][8], Wh[4][8]; // 128 + 128 VGPRs
    {
      const bf16x8* bi = (const bf16x8*)pk2i + (size_t)n * 32768;
      const bf16x8* bh = (const bf16x8*)pk2h + (size_t)n * 32768;
#pragma unroll
      for (int gt = 0; gt < 4; ++gt)
#pragma unroll
        for (int ks = 0; ks < 8; ++ks) {
          size_t o = (size_t)(gt * 16 + q * 4 + wv) * 512 + ks * 64 + lane;
          Wi[gt][ks] = bi[o];
          Wh[gt][ks] = bh[o];
        }
    }
    const int col = q * 64 + wv * 16 + l15;
    float bg[4];
#pragma unroll
    for (int gt = 0; gt < 4; ++gt) {
      int g = gt * 256 + col;
      bg[gt] = bih2[n * kG + g] + bhh2[n * kG + g];
    }
    float cst[2][4];
#pragma unroll
    for (int mt = 0; mt < 2; ++mt)
#pragma unroll
      for (int r = 0; r < 4; ++r) cst[mt][r] = 0.f;

    u64* ringn = h1r + (size_t)n * kD1 * 4096;
    u64* h2n = h2r + (size_t)n * 2 * 4096;
    u32* pg = prog + n * 4 + q;
    __syncthreads();

    // prologue: h1(0), ring slot 0, tag 1
    u64 v1[16], v2[16];
    issue16(ringn, tid, v1);
    finish16(ringn, 1u, tid, v1);

#pragma unroll 1
    for (int t = 0; t < kT; ++t) {
      // (A) stage prefetched h1(t) into hs1
#pragma unroll
      for (int i = 0; i < 16; ++i) {
        hs1[i][tid] = (unsigned short)v1[i];
        hs1[i + 16][tid] = (unsigned short)(v1[i] >> 16);
      }
      __syncthreads();
      if (tid == 0) pstore32(pg, (u32)(t + 1)); // h1(t) consumed; ring slot reusable
      // (B) fire h1(t+1) prefetch; h2(t-1) loads were issued at END of step t-1
      const u64* pn = ringn + (size_t)((t + 1) % kD1) * 4096;
      if (t + 1 < kT) issue16(pn, tid, v1);
      // (C) u = Wih2 * h1(t) + bg2 (h2 propagate+first-sample hidden under A+B+C)
      f32x4 acc[2][4];
#pragma unroll
      for (int mt = 0; mt < 2; ++mt)
#pragma unroll
        for (int gt = 0; gt < 4; ++gt)
#pragma unroll
          for (int r = 0; r < 4; ++r) acc[mt][gt][r] = bg[gt];
#pragma unroll
      for (int ks = 0; ks < 8; ++ks) {
        bf16x8 A0 = *(const bf16x8*)&hs1[l15][ks * 32 + l4 * 8];
        bf16x8 A1 = *(const bf16x8*)&hs1[16 + l15][ks * 32 + l4 * 8];
#pragma unroll
        for (int gt = 0; gt < 4; ++gt) {
          acc[0][gt] = __builtin_amdgcn_mfma_f32_16x16x32_bf16(A0, Wi[gt][ks], acc[0][gt], 0, 0, 0);
          acc[1][gt] = __builtin_amdgcn_mfma_f32_16x16x32_bf16(A1, Wi[gt][ks], acc[1][gt], 0, 0, 0);
        }
      }
      // (D) h2(t-1): validate + stage, then Whh2 MFMA
      if (t > 0) {
        finish16_stage(h2n + (size_t)((t - 1) & 1) * 4096, (u32)t, tid, hs2, v2);
        __syncthreads();
#pragma unroll
        for (int ks = 0; ks < 8; ++ks) {
          bf16x8 A0 = *(const bf16x8*)&hs2[l15][ks * 32 + l4 * 8];
          bf16x8 A1 = *(const bf16x8*)&hs2[16 + l15][ks * 32 + l4 * 8];
#pragma unroll
          for (int gt = 0; gt < 4; ++gt) {
            acc[0][gt] = __builtin_amdgcn_mfma_f32_16x16x32_bf16(A0, Wh[gt][ks], acc[0][gt], 0, 0, 0);
            acc[1][gt] = __builtin_amdgcn_mfma_f32_16x16x32_bf16(A1, Wh[gt][ks], acc[1][gt], 0, 0, 0);
          }
        }
      }
      // (E) cell + publish interleaved by r: each packet out as soon as ready
      u64* pub = h2n + (size_t)(t & 1) * 4096;
      const u64 tagw = ((u64)(u32)(t + 1)) << 32;
      float hv[2][4];
#pragma unroll
      for (int r = 0; r < 4; ++r) {
#pragma unroll
        for (int mt = 0; mt < 2; ++mt) {
          float cc = sigm(acc[mt][1][r]) * cst[mt][r]
                   + sigm(acc[mt][0][r]) * tanh_f(acc[mt][2][r]);
          cst[mt][r] = cc;
          hv[mt][r] = sigm(acc[mt][3][r]) * tanh_f(cc);
        }
        pstore(&pub[(size_t)(l4 * 4 + r) * 256 + col],
               tagw | ((u64)f2bf(hv[1][r]) << 16) | f2bf(hv[0][r]));
      }
      if (t == kT - 1) {
#pragma unroll
        for (int mt = 0; mt < 2; ++mt)
#pragma unroll
          for (int r = 0; r < 4; ++r)
            h2_final[((size_t)n * kB + (mt * 16 + l4 * 4 + r)) * kH + col] = hv[mt][r];
      }
      // (E2) EARLY ISSUE: all 4 quarters write h2(t) into this slot; fire loads now
      // so propagation overlaps (F) + barrier + next step's (A)+(B)+(C).
      if (t + 1 < kT) issue16(pub, tid, v2);
      // (F) validate h1(t+1) prefetch (usually already arrived)
      if (t + 1 < kT) finish16(pn, (u32)(t + 2), tid, v1);
      __syncthreads(); // all MFMA reads done before staging at next (A)
    }
    // signal completion (heaters exit when all 144 L2 WGs are done)
    if (tid == 0)
      __hip_atomic_fetch_add(ndone, 1u, __ATOMIC_RELAXED, __HIP_MEMORY_SCOPE_AGENT);
  } else {
    // ====== heater: register-only dependent MFMA chain on an idle CU ============
    bf16x8 ha{}, hb{};
    f32x4 d = {0.f, 0.f, 0.f, 0.f};
    for (;;) {
#pragma unroll
      for (int i = 0; i < 128; ++i)
        d = __builtin_amdgcn_mfma_f32_16x16x32_bf16(ha, hb, d, 0, 0, 0);
      asm volatile("" ::"v"(d)); // keep the chain live (rule #17)
      if (pload32(ndone) >= 144u) break;
    }
  }
}

// ---- head ----
__global__ __launch_bounds__(256) void k_head1(
    const float* __restrict__ spec, const float* __restrict__ Wspec,
    const float* __restrict__ bspec, const float* __restrict__ Wp1,
    const float* __restrict__ h2f, float* __restrict__ partial)
{
  const int kc = blockIdx.x;
  const int b = blockIdx.y;
  const int o = threadIdx.x;
  __shared__ float fs[kH];
  if (kc < kN) {
    fs[o] = h2f[((size_t)kc * kB + b) * kH + o];
  } else {
    float v = bspec[o];
#pragma unroll
    for (int s = 0; s < kSpec; ++s) v += spec[b * kSpec + s] * Wspec[s * kH + o];
    fs[o] = v;
  }
  __syncthreads();
  const float* __restrict__ wp = Wp1 + (size_t)kc * 256 * kH + o;
  float a = 0.f;
#pragma unroll 8
  for (int i = 0; i < 256; ++i) a += fs[i] * wp[(size_t)i * kH];
  partial[((size_t)kc * kB + b) * kH + o] = a;
}

__global__ __launch_bounds__(256) void k_head2(
    const float* __restrict__ bp1, const float* __restrict__ Wp2,
    const float* __restrict__ bp2, const float* __restrict__ partial,
    float* __restrict__ out)
{
  const int b = blockIdx.x;
  const int o = threadIdx.x;
  __shared__ float hid[kH];
  float a = bp1[o];
#pragma unroll
  for (int kc = 0; kc < kN + 1; ++kc) a += partial[((size_t)kc * kB + b) * kH + o];
  hid[o] = fmaxf(a, 0.f);
  __syncthreads();
  if (o < kOut) {
    float r = bp2[o];
#pragma unroll 8
    for (int h = 0; h < kH; ++h) r += hid[h] * Wp2[h * kOut + o];
    out[b * kOut + o] = r;
  }
}

extern "C" void kernel_launch(void* const* d_in, const int* in_sizes, int n_in,
                              void* d_out, int out_size, void* d_ws, size_t ws_size,
                              hipStream_t stream) {
  const float* x = (const float*)d_in[0];
  const float* spec = (const float*)d_in[1];
  const float* Wih1 = (const float*)d_in[2];
  const float* Whh1 = (const float*)d_in[3];
  const float* bih1 = (const float*)d_in[4];
  const float* bhh1 = (const float*)d_in[5];
  const float* Wih2 = (const float*)d_in[6];
  const float* Whh2 = (const float*)d_in[7];
  const float* bih2 = (const float*)d_in[8];
  const float* bhh2 = (const float*)d_in[9];
  const float* Wspec = (const float*)d_in[10];
  const float* bspec = (const float*)d_in[11];
  const float* Wp1 = (const float*)d_in[12];
  const float* bp1 = (const float*)d_in[13];
  const float* Wp2 = (const float*)d_in[14];
  const float* bp2 = (const float*)d_in[15];
  float* out = (float*)d_out;

  // ws (~80 MB): [prog+ndone 4K][h1r 18.9M][h2r 2.4M][pk1|pk2i|pk2h 56.6M]
  //              [h2_final][partial]
  // Only the 4KB prog page is memset (covers prog + ndone); tagged rings are
  // self-validating (stale tags never match).
  const size_t WSZ = (size_t)kN * kG * kH;
  u32* prog = (u32*)d_ws;
  u64* h1r = (u64*)((char*)d_ws + 4096);                    // 36*16*4096 u64 = 18.87 MB
  u64* h2r = h1r + (size_t)kN * kD1 * 4096;                 // 36*2*4096 u64 = 2.36 MB
  bf16* pk1 = (bf16*)(h2r + (size_t)kN * 2 * 4096);
  bf16* pk2i = pk1 + WSZ;
  bf16* pk2h = pk2i + WSZ;
  float* h2_final = (float*)(pk2h + WSZ);
  float* partial = h2_final + (size_t)kN * kB * kH;

  hipMemsetAsync(d_ws, 0, 4096, stream); // progress counters + ndone

  const size_t groups = (size_t)kN * 64 * 8 * 64;
  k_convert<<<dim3((unsigned)((groups + 255) / 256)), dim3(256), 0, stream>>>(
      Whh1, Wih2, Whh2, pk1, pk2i, pk2h);
  k_lstm<<<dim3(256), dim3(256), 0, stream>>>(
      x, Wih1, bih1, bhh1, bih2, bhh2, pk1, pk2i, pk2h, h2_final, h1r, h2r, prog);
  k_head1<<<dim3(kN + 1, kB), dim3(256), 0, stream>>>(spec, Wspec, bspec, Wp1, h2_final, partial);
  k_head2<<<dim3(kB), dim3(256), 0, stream>>>(bp1, Wp2, bp2, partial, out);
}

// Round 10
// 879.951 us; speedup vs baseline: 2.1343x; 1.0204x over previous
//
#include <hip/hip_runtime.h>
#include <cstdint>
#include <cstddef>

// LSTMClassifier R16 = exact revert to R11 (empirical best, 875.1us).
// Ten-experiment bracket (R6-R15): traffic(R7), RTT-count(R9), VALU(R10),
// issue-timing(R11), poll-position(R12/R13), memory-path LLC->XCD-L2 (R14, FETCH
// 715->220MB proven), and clock/DVFS (R15 heaters, MfmaUtil 23.6% proven) are ALL
// off the critical path. Only wait-DETECTION latency (R8, s_sleep removal, -25%)
// ever moved duration. Conclusion: distributed-recurrence visibility-latency floor
// of the 6-WG/stream topology (register capacity pins >=2 WGs per layer: Whh1=512KB
// = 2 CU register files, Wih2+Whh2=1MB = 4). ~875us is the practical ceiling here.
// This file restores R11 verbatim to lock in the best measured kernel.

constexpr int kN = 36, kH = 256, kG = 1024, kB = 32, kT = 128, kSpec = 6, kOut = 30;
constexpr int kHP = 264;   // LDS h stride (ushort)
constexpr int kD1 = 16;    // h1 ring depth (steps)

typedef __bf16 bf16;
typedef __bf16 bf16x8 __attribute__((ext_vector_type(8)));
typedef float f32x4 __attribute__((ext_vector_type(4)));
typedef unsigned long long u64;
typedef unsigned int u32;

__device__ __forceinline__ float rcpf(float v) { return __builtin_amdgcn_rcpf(v); }
// sigm via v_rcp: exp overflow -> inf -> rcp -> 0; exp underflow -> rcp(1)=1. Safe.
__device__ __forceinline__ float sigm(float v) { return rcpf(1.f + __expf(-v)); }
// tanh = 1 - 2/(1+e^{2v}): v->+inf: rcp(inf)=0 -> 1; v->-inf: rcp(1)=1 -> -1. Safe.
__device__ __forceinline__ float tanh_f(float v) {
  return fmaf(-2.f, rcpf(1.f + __expf(2.f * v)), 1.f);
}
__device__ __forceinline__ unsigned short f2bf(float f) {
  bf16 b = (bf16)f;
  return __builtin_bit_cast(unsigned short, b);
}
__device__ __forceinline__ u64 pload(const u64* p) {
  return __hip_atomic_load(p, __ATOMIC_RELAXED, __HIP_MEMORY_SCOPE_AGENT);
}
__device__ __forceinline__ void pstore(u64* p, u64 v) {
  __hip_atomic_store(p, v, __ATOMIC_RELAXED, __HIP_MEMORY_SCOPE_AGENT);
}
__device__ __forceinline__ u32 pload32(const u32* p) {
  return __hip_atomic_load(p, __ATOMIC_RELAXED, __HIP_MEMORY_SCOPE_AGENT);
}
__device__ __forceinline__ void pstore32(u32* p, u32 v) {
  __hip_atomic_store(p, v, __ATOMIC_RELAXED, __HIP_MEMORY_SCOPE_AGENT);
}

// Packet grid per h-matrix: p = m*256 + c, m=0..15 (rows m and m+16), c=0..255.
// payload: lo16 = row m, hi16 = row m+16, tag = high u32.

// issue 16 loads (p = i*256 + tid), fire-and-forget into v[]
__device__ __forceinline__ void issue16(const u64* __restrict__ base, int tid, u64* v) {
#pragma unroll
  for (int i = 0; i < 16; ++i) v[i] = pload(base + (size_t)i * 256 + tid);
}
// validate all 16 tags == want, re-loading misses (hot spin)
__device__ __forceinline__ void finish16(const u64* __restrict__ base, u32 want,
                                         int tid, u64* v) {
  u32 got = 0;
  for (;;) {
#pragma unroll
    for (int i = 0; i < 16; ++i)
      if (!(got & (1u << i)) && (u32)(v[i] >> 32) == want) got |= 1u << i;
    if (got == 0xFFFFu) return;
#pragma unroll
    for (int i = 0; i < 16; ++i)
      if (!(got & (1u << i))) v[i] = pload(base + (size_t)i * 256 + tid);
  }
}
// validate + stage into hs on detect (col = tid); loads pre-issued in v[]
__device__ __forceinline__ void finish16_stage(const u64* __restrict__ base, u32 want,
                                               int tid, unsigned short (*hs)[kHP],
                                               u64* v) {
  u32 got = 0;
  for (;;) {
#pragma unroll
    for (int i = 0; i < 16; ++i) {
      if (!(got & (1u << i)) && (u32)(v[i] >> 32) == want) {
        got |= 1u << i;
        hs[i][tid] = (unsigned short)v[i];
        hs[i + 16][tid] = (unsigned short)(v[i] >> 16);
      }
    }
    if (got == 0xFFFFu) return;
#pragma unroll
    for (int i = 0; i < 16; ++i)
      if (!(got & (1u << i))) v[i] = pload(base + (size_t)i * 256 + tid);
  }
}
// L1 sibling half: 8 packets/thread over cols [pc0,pc0+128)
__device__ __forceinline__ void issue8h(const u64* __restrict__ base, int tid, int pc0,
                                        u64* v) {
  const int c = pc0 + (tid & 127), m0 = (tid >> 7) * 8;
#pragma unroll
  for (int i = 0; i < 8; ++i) v[i] = pload(base + (size_t)(m0 + i) * 256 + c);
}
__device__ __forceinline__ void finish8_stage(const u64* __restrict__ base, u32 want,
                                              int tid, int pc0,
                                              unsigned short (*hs)[kHP], u64* v) {
  const int c = pc0 + (tid & 127), m0 = (tid >> 7) * 8;
  u32 got = 0;
  for (;;) {
#pragma unroll
    for (int i = 0; i < 8; ++i) {
      if (!(got & (1u << i)) && (u32)(v[i] >> 32) == want) {
        got |= 1u << i;
        hs[m0 + i][c] = (unsigned short)v[i];
        hs[m0 + i + 16][c] = (unsigned short)(v[i] >> 16);
      }
    }
    if (got == 0xFFu) return;
#pragma unroll
    for (int i = 0; i < 8; ++i)
      if (!(got & (1u << i))) v[i] = pload(base + (size_t)(m0 + i) * 256 + c);
  }
}

// ---- convert + permute weights fp32 -> bf16 MFMA B-fragment order ----
__global__ __launch_bounds__(256) void k_convert(
    const float* __restrict__ wa, const float* __restrict__ wb, const float* __restrict__ wc,
    bf16* __restrict__ oa, bf16* __restrict__ ob, bf16* __restrict__ oc)
{
  const size_t total = (size_t)kN * 64 * 8 * 64;
  size_t gid = (size_t)blockIdx.x * 256 + threadIdx.x;
  if (gid >= total) return;
  const int lane = (int)(gid & 63);
  const int ks = (int)((gid >> 6) & 7);
  const int nt = (int)((gid >> 9) & 63);
  const int n = (int)(gid >> 15);
  const int g = nt * 16 + (lane & 15);
  const int k = ks * 32 + (lane >> 4) * 8;
  const size_t so = ((size_t)n * kG + g) * kH + k;

  const float4 a0 = *(const float4*)(wa + so), a1 = *(const float4*)(wa + so + 4);
  const float4 b0 = *(const float4*)(wb + so), b1 = *(const float4*)(wb + so + 4);
  const float4 c0 = *(const float4*)(wc + so), c1 = *(const float4*)(wc + so + 4);
  bf16x8 va, vb, vc;
  va[0]=(bf16)a0.x; va[1]=(bf16)a0.y; va[2]=(bf16)a0.z; va[3]=(bf16)a0.w;
  va[4]=(bf16)a1.x; va[5]=(bf16)a1.y; va[6]=(bf16)a1.z; va[7]=(bf16)a1.w;
  vb[0]=(bf16)b0.x; vb[1]=(bf16)b0.y; vb[2]=(bf16)b0.z; vb[3]=(bf16)b0.w;
  vb[4]=(bf16)b1.x; vb[5]=(bf16)b1.y; vb[6]=(bf16)b1.z; vb[7]=(bf16)b1.w;
  vc[0]=(bf16)c0.x; vc[1]=(bf16)c0.y; vc[2]=(bf16)c0.z; vc[3]=(bf16)c0.w;
  vc[4]=(bf16)c1.x; vc[5]=(bf16)c1.y; vc[6]=(bf16)c1.z; vc[7]=(bf16)c1.w;
  ((bf16x8*)oa)[gid] = va;
  ((bf16x8*)ob)[gid] = vb;
  ((bf16x8*)oc)[gid] = vc;
}

// MFMA over 4 K-slices [KS0, KS0+4) of hs1 against W (L1). KS0 must be a literal.
#define L1_MFMA_HALF(KS0)                                                            \
  _Pragma("unroll")                                                                  \
  for (int kk = 0; kk < 4; ++kk) {                                                   \
    const int ks = (KS0) + kk;                                                       \
    bf16x8 A0 = *(const bf16x8*)&hs1[l15][ks * 32 + l4 * 8];                         \
    bf16x8 A1 = *(const bf16x8*)&hs1[16 + l15][ks * 32 + l4 * 8];                    \
    _Pragma("unroll")                                                                \
    for (int jj = 0; jj < 2; ++jj)                                                   \
      _Pragma("unroll")                                                              \
      for (int gt = 0; gt < 4; ++gt) {                                               \
        acc[0][jj][gt] = __builtin_amdgcn_mfma_f32_16x16x32_bf16(                    \
            A0, W[jj][gt][ks], acc[0][jj][gt], 0, 0, 0);                             \
        acc[1][jj][gt] = __builtin_amdgcn_mfma_f32_16x16x32_bf16(                    \
            A1, W[jj][gt][ks], acc[1][jj][gt], 0, 0, 0);                             \
      }                                                                              \
  }

// ---- two concurrent recurrent chains ----
__global__ __launch_bounds__(256) __attribute__((amdgpu_waves_per_eu(1, 1)))
void k_lstm(
    const float* __restrict__ x, const float* __restrict__ Wih1,
    const float* __restrict__ bih1, const float* __restrict__ bhh1,
    const float* __restrict__ bih2, const float* __restrict__ bhh2,
    const bf16* __restrict__ pk1, const bf16* __restrict__ pk2i,
    const bf16* __restrict__ pk2h, float* __restrict__ h2_final,
    u64* __restrict__ h1r, u64* __restrict__ h2r, u32* __restrict__ prog)
{
  const int blk = blockIdx.x;
  const int tid = threadIdx.x, wv = tid >> 6, lane = tid & 63;
  const int l15 = lane & 15, l4 = lane >> 4;

  __shared__ alignas(16) unsigned short hs1[kB][kHP];

  if (blk < 72) {
    // ================= L1: h1 chain; WG j owns h1-cols [j*128,(j+1)*128) =========
    const int n = blk >> 1, j = blk & 1;
    __shared__ float xsh[kT][kB];
    for (int i = tid; i < kB * kT; i += 256) {
      int b = i >> 7, t = i & 127;
      xsh[t][b] = x[((size_t)b * kT + t) * kN + n];
    }
    bf16x8 W[2][4][8]; // 256 VGPRs
    {
      const bf16x8* base = (const bf16x8*)pk1 + (size_t)n * 32768;
#pragma unroll
      for (int jj = 0; jj < 2; ++jj)
#pragma unroll
        for (int gt = 0; gt < 4; ++gt)
#pragma unroll
          for (int ks = 0; ks < 8; ++ks)
            W[jj][gt][ks] = base[(size_t)(gt * 16 + j * 8 + wv * 2 + jj) * 512 + ks * 64 + lane];
    }
    float wih[2][4], bg[2][4];
#pragma unroll
    for (int jj = 0; jj < 2; ++jj)
#pragma unroll
      for (int gt = 0; gt < 4; ++gt) {
        int g = gt * 256 + j * 128 + wv * 32 + jj * 16 + l15;
        wih[jj][gt] = Wih1[n * kG + g];
        bg[jj][gt] = bih1[n * kG + g] + bhh1[n * kG + g];
      }
    float cst[2][2][4];
#pragma unroll
    for (int a = 0; a < 2; ++a)
#pragma unroll
      for (int b = 0; b < 2; ++b)
#pragma unroll
        for (int r = 0; r < 4; ++r) cst[a][b][r] = 0.f;

    u64* ringn = h1r + (size_t)n * kD1 * 4096;
    u32* pg = prog + n * 4;
    const int pc0 = (1 - j) * 128, myb = j * 128 + wv * 32;
    u64 pv[8]; // sibling prefetch, issued at end of step t for use at t+1
    __syncthreads();

#pragma unroll 1
    for (int t = 0; t < kT; ++t) {
      if ((t & 7) == 0 && t) { // ring back-pressure vs slowest L2 quarter
        if (tid == 0) {
          for (;;) {
            u32 m0 = pload32(&pg[0]), m1 = pload32(&pg[1]);
            u32 m2 = pload32(&pg[2]), m3 = pload32(&pg[3]);
            u32 mn = m0 < m1 ? m0 : m1;
            mn = mn < m2 ? mn : m2;
            mn = mn < m3 ? mn : m3;
            if ((int)mn + 8 >= t) break;
          }
        }
        __syncthreads();
      }
      f32x4 acc[2][2][4];
#pragma unroll
      for (int mt = 0; mt < 2; ++mt)
#pragma unroll
        for (int jj = 0; jj < 2; ++jj)
#pragma unroll
          for (int gt = 0; gt < 4; ++gt)
#pragma unroll
            for (int r = 0; r < 4; ++r)
              acc[mt][jj][gt][r] = xsh[t][mt * 16 + l4 * 4 + r] * wih[jj][gt] + bg[jj][gt];
      if (t > 0) {
        const u64* ps = ringn + (size_t)((t - 1) % kD1) * 4096;
        // own K-half first (LDS-resident since end-of-step t-1 barrier); sibling
        // loads were issued at END of step t-1 -> propagate overlapped cell+publish.
        if (j == 0) { L1_MFMA_HALF(0) } else { L1_MFMA_HALF(4) }
        finish8_stage(ps, (u32)t, tid, pc0, hs1, pv);
        __syncthreads();                    // sibling staged, visible to all waves
        if (j == 0) { L1_MFMA_HALF(4) } else { L1_MFMA_HALF(0) }
      }
      // cell + publish interleaved by jj: packets go out as soon as ready
      u64* pub = ringn + (size_t)(t % kD1) * 4096;
      const u64 tagw = ((u64)(u32)(t + 1)) << 32;
      float hv[2][2][4];
#pragma unroll
      for (int jj = 0; jj < 2; ++jj) {
#pragma unroll
        for (int mt = 0; mt < 2; ++mt)
#pragma unroll
          for (int r = 0; r < 4; ++r) {
            float cc = sigm(acc[mt][jj][1][r]) * cst[mt][jj][r]
                     + sigm(acc[mt][jj][0][r]) * tanh_f(acc[mt][jj][2][r]);
            cst[mt][jj][r] = cc;
            hv[mt][jj][r] = sigm(acc[mt][jj][3][r]) * tanh_f(cc);
          }
#pragma unroll
        for (int r = 0; r < 4; ++r) {
          int c = myb + jj * 16 + l15, m = l4 * 4 + r;
          pstore(&pub[(size_t)m * 256 + c],
                 tagw | ((u64)f2bf(hv[1][jj][r]) << 16) | f2bf(hv[0][jj][r]));
        }
      }
      // own half straight into LDS for next step
#pragma unroll
      for (int mt = 0; mt < 2; ++mt)
#pragma unroll
        for (int jj = 0; jj < 2; ++jj)
#pragma unroll
          for (int r = 0; r < 4; ++r)
            hs1[mt * 16 + l4 * 4 + r][myb + jj * 16 + l15] = f2bf(hv[mt][jj][r]);
      // EARLY ISSUE: sibling writes h1(t) into this same slot; fire loads now so
      // propagation + first sample overlap the rest of this step + barrier.
      if (t + 1 < kT) issue8h(pub, tid, pc0, pv);
      __syncthreads(); // own-half visible for next step's pre-barrier own-K MFMA
    }
  } else {
    // ====== L2: h2 chain; WG q owns h2-cols [q*64,(q+1)*64); u in-register =======
    const int bb = blk - 72, n = bb >> 2, q = bb & 3;
    __shared__ alignas(16) unsigned short hs2[kB][kHP];

    bf16x8 Wi[4][8], Wh[4][8]; // 128 + 128 VGPRs
    {
      const bf16x8* bi = (const bf16x8*)pk2i + (size_t)n * 32768;
      const bf16x8* bh = (const bf16x8*)pk2h + (size_t)n * 32768;
#pragma unroll
      for (int gt = 0; gt < 4; ++gt)
#pragma unroll
        for (int ks = 0; ks < 8; ++ks) {
          size_t o = (size_t)(gt * 16 + q * 4 + wv) * 512 + ks * 64 + lane;
          Wi[gt][ks] = bi[o];
          Wh[gt][ks] = bh[o];
        }
    }
    const int col = q * 64 + wv * 16 + l15;
    float bg[4];
#pragma unroll
    for (int gt = 0; gt < 4; ++gt) {
      int g = gt * 256 + col;
      bg[gt] = bih2[n * kG + g] + bhh2[n * kG + g];
    }
    float cst[2][4];
#pragma unroll
    for (int mt = 0; mt < 2; ++mt)
#pragma unroll
      for (int r = 0; r < 4; ++r) cst[mt][r] = 0.f;

    u64* ringn = h1r + (size_t)n * kD1 * 4096;
    u64* h2n = h2r + (size_t)n * 2 * 4096;
    u32* pg = prog + n * 4 + q;
    __syncthreads();

    // prologue: h1(0), ring slot 0, tag 1
    u64 v1[16], v2[16];
    issue16(ringn, tid, v1);
    finish16(ringn, 1u, tid, v1);

#pragma unroll 1
    for (int t = 0; t < kT; ++t) {
      // (A) stage prefetched h1(t) into hs1
#pragma unroll
      for (int i = 0; i < 16; ++i) {
        hs1[i][tid] = (unsigned short)v1[i];
        hs1[i + 16][tid] = (unsigned short)(v1[i] >> 16);
      }
      __syncthreads();
      if (tid == 0) pstore32(pg, (u32)(t + 1)); // h1(t) consumed; ring slot reusable
      // (B) fire h1(t+1) prefetch; h2(t-1) loads were issued at END of step t-1
      const u64* pn = ringn + (size_t)((t + 1) % kD1) * 4096;
      if (t + 1 < kT) issue16(pn, tid, v1);
      // (C) u = Wih2 * h1(t) + bg2 (h2 propagate+first-sample hidden under A+B+C)
      f32x4 acc[2][4];
#pragma unroll
      for (int mt = 0; mt < 2; ++mt)
#pragma unroll
        for (int gt = 0; gt < 4; ++gt)
#pragma unroll
          for (int r = 0; r < 4; ++r) acc[mt][gt][r] = bg[gt];
#pragma unroll
      for (int ks = 0; ks < 8; ++ks) {
        bf16x8 A0 = *(const bf16x8*)&hs1[l15][ks * 32 + l4 * 8];
        bf16x8 A1 = *(const bf16x8*)&hs1[16 + l15][ks * 32 + l4 * 8];
#pragma unroll
        for (int gt = 0; gt < 4; ++gt) {
          acc[0][gt] = __builtin_amdgcn_mfma_f32_16x16x32_bf16(A0, Wi[gt][ks], acc[0][gt], 0, 0, 0);
          acc[1][gt] = __builtin_amdgcn_mfma_f32_16x16x32_bf16(A1, Wi[gt][ks], acc[1][gt], 0, 0, 0);
        }
      }
      // (D) h2(t-1): validate + stage, then Whh2 MFMA
      if (t > 0) {
        finish16_stage(h2n + (size_t)((t - 1) & 1) * 4096, (u32)t, tid, hs2, v2);
        __syncthreads();
#pragma unroll
        for (int ks = 0; ks < 8; ++ks) {
          bf16x8 A0 = *(const bf16x8*)&hs2[l15][ks * 32 + l4 * 8];
          bf16x8 A1 = *(const bf16x8*)&hs2[16 + l15][ks * 32 + l4 * 8];
#pragma unroll
          for (int gt = 0; gt < 4; ++gt) {
            acc[0][gt] = __builtin_amdgcn_mfma_f32_16x16x32_bf16(A0, Wh[gt][ks], acc[0][gt], 0, 0, 0);
            acc[1][gt] = __builtin_amdgcn_mfma_f32_16x16x32_bf16(A1, Wh[gt][ks], acc[1][gt], 0, 0, 0);
          }
        }
      }
      // (E) cell + publish interleaved by r: each packet out as soon as ready
      u64* pub = h2n + (size_t)(t & 1) * 4096;
      const u64 tagw = ((u64)(u32)(t + 1)) << 32;
      float hv[2][4];
#pragma unroll
      for (int r = 0; r < 4; ++r) {
#pragma unroll
        for (int mt = 0; mt < 2; ++mt) {
          float cc = sigm(acc[mt][1][r]) * cst[mt][r]
                   + sigm(acc[mt][0][r]) * tanh_f(acc[mt][2][r]);
          cst[mt][r] = cc;
          hv[mt][r] = sigm(acc[mt][3][r]) * tanh_f(cc);
        }
        pstore(&pub[(size_t)(l4 * 4 + r) * 256 + col],
               tagw | ((u64)f2bf(hv[1][r]) << 16) | f2bf(hv[0][r]));
      }
      if (t == kT - 1) {
#pragma unroll
        for (int mt = 0; mt < 2; ++mt)
#pragma unroll
          for (int r = 0; r < 4; ++r)
            h2_final[((size_t)n * kB + (mt * 16 + l4 * 4 + r)) * kH + col] = hv[mt][r];
      }
      // (E2) EARLY ISSUE: all 4 quarters write h2(t) into this slot; fire loads now
      // so propagation overlaps (F) + barrier + next step's (A)+(B)+(C).
      if (t + 1 < kT) issue16(pub, tid, v2);
      // (F) validate h1(t+1) prefetch (usually already arrived)
      if (t + 1 < kT) finish16(pn, (u32)(t + 2), tid, v1);
      __syncthreads(); // all MFMA reads done before staging at next (A)
    }
  }
}

// ---- head ----
__global__ __launch_bounds__(256) void k_head1(
    const float* __restrict__ spec, const float* __restrict__ Wspec,
    const float* __restrict__ bspec, const float* __restrict__ Wp1,
    const float* __restrict__ h2f, float* __restrict__ partial)
{
  const int kc = blockIdx.x;
  const int b = blockIdx.y;
  const int o = threadIdx.x;
  __shared__ float fs[kH];
  if (kc < kN) {
    fs[o] = h2f[((size_t)kc * kB + b) * kH + o];
  } else {
    float v = bspec[o];
#pragma unroll
    for (int s = 0; s < kSpec; ++s) v += spec[b * kSpec + s] * Wspec[s * kH + o];
    fs[o] = v;
  }
  __syncthreads();
  const float* __restrict__ wp = Wp1 + (size_t)kc * 256 * kH + o;
  float a = 0.f;
#pragma unroll 8
  for (int i = 0; i < 256; ++i) a += fs[i] * wp[(size_t)i * kH];
  partial[((size_t)kc * kB + b) * kH + o] = a;
}

__global__ __launch_bounds__(256) void k_head2(
    const float* __restrict__ bp1, const float* __restrict__ Wp2,
    const float* __restrict__ bp2, const float* __restrict__ partial,
    float* __restrict__ out)
{
  const int b = blockIdx.x;
  const int o = threadIdx.x;
  __shared__ float hid[kH];
  float a = bp1[o];
#pragma unroll
  for (int kc = 0; kc < kN + 1; ++kc) a += partial[((size_t)kc * kB + b) * kH + o];
  hid[o] = fmaxf(a, 0.f);
  __syncthreads();
  if (o < kOut) {
    float r = bp2[o];
#pragma unroll 8
    for (int h = 0; h < kH; ++h) r += hid[h] * Wp2[h * kOut + o];
    out[b * kOut + o] = r;
  }
}

extern "C" void kernel_launch(void* const* d_in, const int* in_sizes, int n_in,
                              void* d_out, int out_size, void* d_ws, size_t ws_size,
                              hipStream_t stream) {
  const float* x = (const float*)d_in[0];
  const float* spec = (const float*)d_in[1];
  const float* Wih1 = (const float*)d_in[2];
  const float* Whh1 = (const float*)d_in[3];
  const float* bih1 = (const float*)d_in[4];
  const float* bhh1 = (const float*)d_in[5];
  const float* Wih2 = (const float*)d_in[6];
  const float* Whh2 = (const float*)d_in[7];
  const float* bih2 = (const float*)d_in[8];
  const float* bhh2 = (const float*)d_in[9];
  const float* Wspec = (const float*)d_in[10];
  const float* bspec = (const float*)d_in[11];
  const float* Wp1 = (const float*)d_in[12];
  const float* bp1 = (const float*)d_in[13];
  const float* Wp2 = (const float*)d_in[14];
  const float* bp2 = (const float*)d_in[15];
  float* out = (float*)d_out;

  // ws (~80 MB): [prog 4K][h1r 18.9M][h2r 2.4M][pk1|pk2i|pk2h 56.6M][h2_final][partial]
  // Only prog is memset; tagged rings are self-validating (stale tags never match).
  const size_t WSZ = (size_t)kN * kG * kH;
  u32* prog = (u32*)d_ws;
  u64* h1r = (u64*)((char*)d_ws + 4096);                    // 36*16*4096 u64 = 18.87 MB
  u64* h2r = h1r + (size_t)kN * kD1 * 4096;                 // 36*2*4096 u64 = 2.36 MB
  bf16* pk1 = (bf16*)(h2r + (size_t)kN * 2 * 4096);
  bf16* pk2i = pk1 + WSZ;
  bf16* pk2h = pk2i + WSZ;
  float* h2_final = (float*)(pk2h + WSZ);
  float* partial = h2_final + (size_t)kN * kB * kH;

  hipMemsetAsync(d_ws, 0, 4096, stream); // progress counters only

  const size_t groups = (size_t)kN * 64 * 8 * 64;
  k_convert<<<dim3((unsigned)((groups + 255) / 256)), dim3(256), 0, stream>>>(
      Whh1, Wih2, Whh2, pk1, pk2i, pk2h);
  k_lstm<<<dim3(216), dim3(256), 0, stream>>>(
      x, Wih1, bih1, bhh1, bih2, bhh2, pk1, pk2i, pk2h, h2_final, h1r, h2r, prog);
  k_head1<<<dim3(kN + 1, kB), dim3(256), 0, stream>>>(spec, Wspec, bspec, Wp1, h2_final, partial);
  k_head2<<<dim3(kB), dim3(256), 0, stream>>>(bp1, Wp2, bp2, partial, out);
}